// Round 1
// baseline (981.324 us; speedup 1.0000x reference)
//
#include <hip/hip_runtime.h>
#include <hip/hip_bf16.h>
#include <stdint.h>

// ---------------------------------------------------------------------------
// TransformerBlock fused forward for MI355X (gfx950).
// Shapes (fixed): B=8 TQ=512 TK=2048 D=1024 H=16 HD=64 NE=4 HID=32 NA=512.
//
// Key choices (round 1):
//  * bf16 MFMA (v_mfma_f32_16x16x32_bf16) for all 6 GEMMs, m97 structure:
//    128x128 tile, BK=32, 4 waves, global_load_lds width=16, fp32 accum.
//    Weights are converted fp32->bf16 AND transposed to (N,K) on device so
//    both A and W LDS tiles stage linearly and frag reads are ds_read_b128.
//  * probs = softmax(x@Wr + br): the reference adds sim (constant across the
//    expert axis) before softmax -> shift-invariance makes q_vec/sim DEAD.
//  * MoE contraction: moe_out = concat_e(probs_e*act_e) @ vstack_e(W2_e);
//    probs-weighted b2 folded into the final elementwise kernel.
//  * Attention: fp32 register-tiled flash, two segments (active/inactive),
//    64 q-rows per block, 64-wide K/V tiles, XOR-swizzled Ps/Vs LDS.
// Workspace: ~153 MB (all offsets below; buffers reused after last consumer).
// ---------------------------------------------------------------------------

#define B_   8
#define TQ_  512
#define TK_  2048
#define D_   1024
#define H_   16
#define HD_  64
#define NE_  4
#define HID_ 32
#define EPSF 1e-6f

typedef __bf16 bf16_t;
typedef __bf16 bf16x8 __attribute__((ext_vector_type(8)));
typedef __bf16 bf16x4 __attribute__((ext_vector_type(4)));
typedef float  f32x4  __attribute__((ext_vector_type(4)));

typedef __attribute__((address_space(1))) void gvoid_t;
typedef __attribute__((address_space(3))) void lvoid_t;

__device__ __forceinline__ void gld_lds16(const void* g, void* l) {
  // async global->LDS, 16B per lane; LDS dest is wave-uniform-base + lane*16
  __builtin_amdgcn_global_load_lds((gvoid_t*)g, (lvoid_t*)l, 16, 0, 0);
}

// ---------------------------------------------------------------------------
// Weight convert + transpose: out[(c + bz*ob_row)*out_rstride + bz*ob_col + r]
//   = (bf16) in[bz*in_bstride + r*C + c]
// ---------------------------------------------------------------------------
__global__ void transpose_conv_kernel(const float* __restrict__ in, bf16_t* __restrict__ out,
                                      int R, int C, int in_bstride,
                                      int out_rstride, int ob_row, int ob_col) {
  __shared__ float tile[32][33];
  const int bz = blockIdx.z;
  const int rb = blockIdx.y * 32, cb = blockIdx.x * 32;
  const int txi = threadIdx.x, tyi = threadIdx.y;
  const float* inp = in + (size_t)bz * in_bstride;
#pragma unroll
  for (int i = 0; i < 32; i += 8) {
    const int r = rb + tyi + i, c = cb + txi;
    if (r < R && c < C) tile[tyi + i][txi] = inp[(size_t)r * C + c];
  }
  __syncthreads();
#pragma unroll
  for (int i = 0; i < 32; i += 8) {
    const int orow = cb + tyi + i;   // original col
    const int ocol = rb + txi;       // original row
    if (orow < C && ocol < R)
      out[(size_t)(orow + bz * ob_row) * out_rstride + bz * ob_col + ocol] =
          (bf16_t)tile[txi][tyi + i];
  }
}

// ---------------------------------------------------------------------------
// Block-wide (256 thr) sum reduce
// ---------------------------------------------------------------------------
__device__ __forceinline__ float block_rsum(float v, float* red) {
  v += __shfl_xor(v, 1);  v += __shfl_xor(v, 2);  v += __shfl_xor(v, 4);
  v += __shfl_xor(v, 8);  v += __shfl_xor(v, 16); v += __shfl_xor(v, 32);
  const int tid = threadIdx.x;
  if ((tid & 63) == 0) red[tid >> 6] = v;
  __syncthreads();
  return red[0] + red[1] + red[2] + red[3];
}

// ---------------------------------------------------------------------------
// RMSNorm of kv: one block per row. Writes kv_b (seg-dependent w + bias) and
// x = rmsnorm(kv, fn_w), both bf16 — shares one sumsq pass.
// ---------------------------------------------------------------------------
__global__ __launch_bounds__(256)
void rms_kv_kernel(const float* __restrict__ kv, const float* __restrict__ kva_w,
                   const float* __restrict__ kvi_w, const float* __restrict__ fn_w,
                   const float* __restrict__ ab, const float* __restrict__ ib,
                   const int* __restrict__ n_act,
                   bf16_t* __restrict__ kvb, bf16_t* __restrict__ xn) {
  __shared__ float red[4];
  const int row = blockIdx.x;
  const int t = row & (TK_ - 1);
  const int tid = threadIdx.x;
  const float* src = kv + (size_t)row * D_;
  f32x4 v = ((const f32x4*)src)[tid];
  float ss = v[0]*v[0] + v[1]*v[1] + v[2]*v[2] + v[3]*v[3];
  ss = block_rsum(ss, red);
  const float rs = rsqrtf(ss * (1.0f / D_) + EPSF);
  const int Na = n_act[0];
  const float* wsel = (t < Na) ? kva_w : kvi_w;
  const float* bsel = (t < Na) ? ab : ib;
  const int d = tid * 4;
  f32x4 wv = *(const f32x4*)(wsel + d);
  f32x4 bv = *(const f32x4*)(bsel + d);
  f32x4 fv = *(const f32x4*)(fn_w + d);
  bf16x4 o0, o1;
#pragma unroll
  for (int c = 0; c < 4; ++c) {
    const float xv = v[c] * rs;
    o0[c] = (bf16_t)(xv * wv[c] + bv[c]);
    o1[c] = (bf16_t)(xv * fv[c]);
  }
  *(bf16x4*)&kvb[(size_t)row * D_ + d] = o0;
  *(bf16x4*)&xn [(size_t)row * D_ + d] = o1;
}

__global__ __launch_bounds__(256)
void rms_q_kernel(const float* __restrict__ q, const float* __restrict__ qn_w,
                  bf16_t* __restrict__ qn) {
  __shared__ float red[4];
  const int row = blockIdx.x;
  const int tid = threadIdx.x;
  const float* src = q + (size_t)row * D_;
  f32x4 v = ((const f32x4*)src)[tid];
  float ss = v[0]*v[0] + v[1]*v[1] + v[2]*v[2] + v[3]*v[3];
  ss = block_rsum(ss, red);
  const float rs = rsqrtf(ss * (1.0f / D_) + EPSF);
  const int d = tid * 4;
  f32x4 wv = *(const f32x4*)(qn_w + d);
  bf16x4 o0;
#pragma unroll
  for (int c = 0; c < 4; ++c) o0[c] = (bf16_t)(v[c] * rs * wv[c]);
  *(bf16x4*)&qn[(size_t)row * D_ + d] = o0;
}

// ---------------------------------------------------------------------------
// bf16 MFMA GEMM: C(M,N) = A(M,K) @ Wt(N,K)^T (+ bias[N]), bf16 out, f32 acc.
// 128x128 tile, BK=32, 256 thr (4 waves, 2x2 of 64x64), global_load_lds x16.
// Requires M%128==0, N%128==0 (or N==256 w/ grid.y=2), K%32==0.
// ---------------------------------------------------------------------------
template<int HAS_BIAS>
__global__ __launch_bounds__(256)
void gemm_tn(const bf16_t* __restrict__ A, const bf16_t* __restrict__ Wt,
             const float* __restrict__ bias, bf16_t* __restrict__ C,
             int M, int N, int K) {
  __shared__ alignas(16) bf16_t As[128 * 32];
  __shared__ alignas(16) bf16_t Bs[128 * 32];
  const int tid = threadIdx.x;
  const int lane = tid & 63;
  const int w = tid >> 6;
  const int wr = w >> 1, wc = w & 1;
  const int m0 = blockIdx.x * 128;
  const int n0 = blockIdx.y * 128;

  f32x4 acc[4][4] = {};

  const int eidx = tid * 8;
  const int srow = eidx >> 5;      // 0..63 (issue covers 64 rows of 32 cols)
  const int scol = eidx & 31;
  const bf16_t* ga = A  + (size_t)(m0 + srow) * K + scol;
  const bf16_t* gb = Wt + (size_t)(n0 + srow) * K + scol;
  bf16_t* la0 = &As[tid * 8];
  bf16_t* la1 = &As[2048 + tid * 8];
  bf16_t* lb0 = &Bs[tid * 8];
  bf16_t* lb1 = &Bs[2048 + tid * 8];
  const size_t rstep = (size_t)64 * K;

  const int kb = (lane >> 4) * 8;                    // frag k chunk
  const int ar  = (wr * 64 + (lane & 15)) * 32 + kb; // A frag base
  const int br2 = (wc * 64 + (lane & 15)) * 32 + kb; // W frag base

  for (int k0 = 0; k0 < K; k0 += 32) {
    gld_lds16(ga + k0,         la0);
    gld_lds16(ga + k0 + rstep, la1);
    gld_lds16(gb + k0,         lb0);
    gld_lds16(gb + k0 + rstep, lb1);
    __syncthreads();
    bf16x8 af[4], bfr[4];
#pragma unroll
    for (int i = 0; i < 4; ++i) af[i]  = *(const bf16x8*)&As[ar  + i * 512];
#pragma unroll
    for (int j = 0; j < 4; ++j) bfr[j] = *(const bf16x8*)&Bs[br2 + j * 512];
#pragma unroll
    for (int i = 0; i < 4; ++i)
#pragma unroll
      for (int j = 0; j < 4; ++j)
        acc[i][j] = __builtin_amdgcn_mfma_f32_16x16x32_bf16(af[i], bfr[j], acc[i][j], 0, 0, 0);
    __syncthreads();
  }

  // C/D layout (m89-verified): col = lane&15, row = (lane>>4)*4 + reg
  const int row0 = m0 + wr * 64 + ((lane >> 4) << 2);
  const int col0 = n0 + wc * 64 + (lane & 15);
#pragma unroll
  for (int j = 0; j < 4; ++j) {
    const int cc = col0 + j * 16;
    const float bv = HAS_BIAS ? bias[cc] : 0.0f;
#pragma unroll
    for (int i = 0; i < 4; ++i) {
      const int rr = row0 + i * 16;
#pragma unroll
      for (int r = 0; r < 4; ++r)
        C[(size_t)(rr + r) * N + cc] = (bf16_t)(acc[i][j][r] + bv);
    }
  }
}

// ---------------------------------------------------------------------------
// Two-segment flash attention, fp32 register-tiled.
// Block = 256 thr handles (b, h, 64 q-rows); K/V tiles of 64.
// out = softmaxA@V/sqrt(Na) - softmaxI@V/sqrt(Ni), scale=1/(HD*temp) in Q.
// LDS exactly 64KB: Qs,Ks (transposed [d][r/c]), Vs,Ps (XOR-swizzled cols).
// ---------------------------------------------------------------------------
__global__ __launch_bounds__(256)
void attn_kernel(const bf16_t* __restrict__ qp, const bf16_t* __restrict__ kb,
                 const bf16_t* __restrict__ vb, bf16_t* __restrict__ attno,
                 const float* __restrict__ log_temp, const int* __restrict__ n_act) {
  __shared__ float Qs[64][64];
  __shared__ float Ks[64][64];
  __shared__ float Vs[64][64];
  __shared__ float Ps[64][64];
  const int bidx = blockIdx.x;
  const int qt = bidx & 7;
  const int h  = (bidx >> 3) & 15;
  const int b  = bidx >> 7;
  const int tid = threadIdx.x;
  const int Na = n_act[0];
  float temp = __expf(log_temp[0]);
  temp = fminf(fmaxf(temp, 0.1f), 10.0f);
  const float scale = 1.0f / (64.0f * temp);
  const int q0 = qt * 64;

  { // load Q tile, scaled, stored transposed Qs[d][r]
    const int r = tid >> 2;
    const int d0s = (tid & 3) * 16;
    const bf16_t* src = qp + (size_t)(b * TQ_ + q0 + r) * D_ + h * 64 + d0s;
    bf16x8 v0 = *(const bf16x8*)src;
    bf16x8 v1 = *(const bf16x8*)(src + 8);
#pragma unroll
    for (int j = 0; j < 8; ++j) Qs[d0s + j][r] = (float)v0[j] * scale;
#pragma unroll
    for (int j = 0; j < 8; ++j) Qs[d0s + 8 + j][r] = (float)v1[j] * scale;
  }

  const int tx = tid & 15, ty = tid >> 4;
  const int r0 = ty * 4, c0 = tx * 4;

  float m_s[4], l_s[4], o[4][4], outa[4][4];
#pragma unroll
  for (int i = 0; i < 4; ++i) {
    m_s[i] = -1e30f; l_s[i] = 0.f;
#pragma unroll
    for (int j = 0; j < 4; ++j) { o[i][j] = 0.f; outa[i][j] = 0.f; }
  }

  const float inv_sa = rsqrtf((float)(Na > 1 ? Na : 1));
  const int Ni = TK_ - Na;
  const float inv_si = rsqrtf((float)(Ni > 1 ? Ni : 1));

  const int cstage = tid >> 2;
  const int dstage = (tid & 3) * 16;

  for (int t = 0; t < TK_ / 64; ++t) {
    __syncthreads();  // prev PV done (and Q load on t==0)
    { // stage K (transposed) and V (swizzled) tiles
      const int k0 = t * 64;
      const bf16_t* ksrc = kb + (size_t)(b * TK_ + k0 + cstage) * D_ + h * 64 + dstage;
      const bf16_t* vsrc = vb + (size_t)(b * TK_ + k0 + cstage) * D_ + h * 64 + dstage;
      bf16x8 k0v = *(const bf16x8*)ksrc;
      bf16x8 k1v = *(const bf16x8*)(ksrc + 8);
      bf16x8 v0v = *(const bf16x8*)vsrc;
      bf16x8 v1v = *(const bf16x8*)(vsrc + 8);
      const int vsw = (cstage & 7) << 2;
#pragma unroll
      for (int j = 0; j < 8; ++j) Ks[dstage + j][cstage] = (float)k0v[j];
#pragma unroll
      for (int j = 0; j < 8; ++j) Ks[dstage + 8 + j][cstage] = (float)k1v[j];
#pragma unroll
      for (int j = 0; j < 8; ++j) Vs[cstage][(dstage + j) ^ vsw] = (float)v0v[j];
#pragma unroll
      for (int j = 0; j < 8; ++j) Vs[cstage][(dstage + 8 + j) ^ vsw] = (float)v1v[j];
    }
    __syncthreads();

    // S = Q @ K^T (register 4x4 per thread)
    float s_[4][4];
#pragma unroll
    for (int i = 0; i < 4; ++i)
#pragma unroll
      for (int j = 0; j < 4; ++j) s_[i][j] = 0.f;
    for (int dd = 0; dd < 64; ++dd) {
      f32x4 q4 = *(const f32x4*)&Qs[dd][r0];
      f32x4 k4 = *(const f32x4*)&Ks[dd][c0];
#pragma unroll
      for (int i = 0; i < 4; ++i)
#pragma unroll
        for (int j = 0; j < 4; ++j) s_[i][j] += q4[i] * k4[j];
    }

    // online softmax update + write P (swizzled)
#pragma unroll
    for (int i = 0; i < 4; ++i) {
      float mt = fmaxf(fmaxf(s_[i][0], s_[i][1]), fmaxf(s_[i][2], s_[i][3]));
      mt = fmaxf(mt, __shfl_xor(mt, 1));
      mt = fmaxf(mt, __shfl_xor(mt, 2));
      mt = fmaxf(mt, __shfl_xor(mt, 4));
      mt = fmaxf(mt, __shfl_xor(mt, 8));
      const float mnew = fmaxf(m_s[i], mt);
      const float f = __expf(m_s[i] - mnew);
      m_s[i] = mnew;
      float ps = 0.f;
#pragma unroll
      for (int j = 0; j < 4; ++j) { const float p = __expf(s_[i][j] - mnew); s_[i][j] = p; ps += p; }
      ps += __shfl_xor(ps, 1); ps += __shfl_xor(ps, 2);
      ps += __shfl_xor(ps, 4); ps += __shfl_xor(ps, 8);
      l_s[i] = l_s[i] * f + ps;
#pragma unroll
      for (int j = 0; j < 4; ++j) o[i][j] *= f;
      const int rr = r0 + i;
      f32x4 pv = { s_[i][0], s_[i][1], s_[i][2], s_[i][3] };
      *(f32x4*)&Ps[rr][c0 ^ ((rr & 7) << 2)] = pv;
    }
    __syncthreads();

    // O += P @ V
    for (int c = 0; c < 64; ++c) {
      const int vsw2 = (c & 7) << 2;
      f32x4 v4 = *(const f32x4*)&Vs[c][c0 ^ vsw2];
#pragma unroll
      for (int i = 0; i < 4; ++i) {
        const int rr = r0 + i;
        const float p = Ps[rr][c ^ ((rr & 7) << 2)];
        o[i][0] += p * v4[0]; o[i][1] += p * v4[1];
        o[i][2] += p * v4[2]; o[i][3] += p * v4[3];
      }
    }

    // segment boundary: finalize running state into output accumulator
    const int kend = (t + 1) * 64;
    const bool endA = (kend == Na);
    const bool endI = (t == TK_ / 64 - 1);
    if (endA || endI) {
      const float ssc = endA ? inv_sa : -inv_si;
#pragma unroll
      for (int i = 0; i < 4; ++i) {
        const float inv = ssc / l_s[i];
#pragma unroll
        for (int j = 0; j < 4; ++j) outa[i][j] += o[i][j] * inv;
        m_s[i] = -1e30f; l_s[i] = 0.f;
#pragma unroll
        for (int j = 0; j < 4; ++j) o[i][j] = 0.f;
      }
    }
  }

#pragma unroll
  for (int i = 0; i < 4; ++i) {
    const int rr = q0 + r0 + i;
    bf16x4 ov;
#pragma unroll
    for (int j = 0; j < 4; ++j) ov[j] = (bf16_t)outa[i][j];
    *(bf16x4*)&attno[(size_t)(b * TQ_ + rr) * D_ + h * 64 + c0] = ov;
  }
}

// ---------------------------------------------------------------------------
// delta = rmsnorm(proj, dn_w); q_new = q + sigmoid(gate_attn)*delta  (fp32 out)
// ---------------------------------------------------------------------------
__global__ __launch_bounds__(256)
void delta_qnew_kernel(const bf16_t* __restrict__ proj, const float* __restrict__ dn_w,
                       const float* __restrict__ q, const float* __restrict__ gate_attn,
                       float* __restrict__ qnew) {
  __shared__ float red[4];
  const int row = blockIdx.x;
  const int tid = threadIdx.x;
  bf16x4 pv = *(const bf16x4*)(proj + (size_t)row * D_ + tid * 4);
  f32x4 v;
#pragma unroll
  for (int c = 0; c < 4; ++c) v[c] = (float)pv[c];
  float ss = v[0]*v[0] + v[1]*v[1] + v[2]*v[2] + v[3]*v[3];
  ss = block_rsum(ss, red);
  const float rs = rsqrtf(ss * (1.0f / D_) + EPSF);
  const float sga = 1.0f / (1.0f + __expf(-gate_attn[0]));
  const int d = tid * 4;
  f32x4 wv = *(const f32x4*)(dn_w + d);
  f32x4 qv = *(const f32x4*)(q + (size_t)row * D_ + d);
  f32x4 out;
#pragma unroll
  for (int c = 0; c < 4; ++c) out[c] = qv[c] + sga * (v[c] * rs * wv[c]);
  *(f32x4*)&qnew[(size_t)row * D_ + d] = out;
}

// ---------------------------------------------------------------------------
// probs = softmax(x @ Wr + br) over NE=4.  (sim term is softmax-shift: dead.)
// One wave per row.
// ---------------------------------------------------------------------------
__global__ __launch_bounds__(256)
void probs_kernel(const bf16_t* __restrict__ xn, const float* __restrict__ Wr,
                  const float* __restrict__ br, float* __restrict__ probs) {
  const int tid = threadIdx.x;
  const int lane = tid & 63;
  const int row = blockIdx.x * 4 + (tid >> 6);
  const bf16_t* xrow = xn + (size_t)row * D_;
  float a0 = 0.f, a1 = 0.f, a2 = 0.f, a3 = 0.f;
  for (int it = 0; it < D_ / 64; ++it) {
    const int d = it * 64 + lane;
    const float xv = (float)xrow[d];
    const f32x4 w4 = *(const f32x4*)&Wr[d * 4];
    a0 += xv * w4[0]; a1 += xv * w4[1]; a2 += xv * w4[2]; a3 += xv * w4[3];
  }
#pragma unroll
  for (int m = 1; m <= 32; m <<= 1) {
    a0 += __shfl_xor(a0, m); a1 += __shfl_xor(a1, m);
    a2 += __shfl_xor(a2, m); a3 += __shfl_xor(a3, m);
  }
  a0 += br[0]; a1 += br[1]; a2 += br[2]; a3 += br[3];
  const float mx = fmaxf(fmaxf(a0, a1), fmaxf(a2, a3));
  const float e0 = __expf(a0 - mx), e1 = __expf(a1 - mx);
  const float e2 = __expf(a2 - mx), e3 = __expf(a3 - mx);
  const float inv = 1.0f / (e0 + e1 + e2 + e3);
  if (lane == 0) {
    f32x4 pr = { e0 * inv, e1 * inv, e2 * inv, e3 * inv };
    *(f32x4*)&probs[row * 4] = pr;
  }
}

// ---------------------------------------------------------------------------
// a2[row][e*32+hh] = probs[row][e] * xp * silu(g);  xp=h[e*64+hh], g=h[e*64+32+hh]
// ---------------------------------------------------------------------------
__global__ __launch_bounds__(256)
void act_kernel(const bf16_t* __restrict__ hbuf, const float* __restrict__ probs,
                bf16_t* __restrict__ a2buf) {
  const int idx = blockIdx.x * 256 + threadIdx.x;  // B*TK*NE*HID
  const int row = idx >> 7;
  const int eh = idx & 127;
  const int e = eh >> 5, hh = eh & 31;
  const float xp = (float)hbuf[(size_t)row * 256 + e * 64 + hh];
  const float g  = (float)hbuf[(size_t)row * 256 + e * 64 + 32 + hh];
  const float sg = 1.0f / (1.0f + __expf(-g));
  a2buf[idx] = (bf16_t)(probs[row * 4 + e] * xp * g * sg);
}

// ---------------------------------------------------------------------------
// kv_new = kv + sigmoid(gate_ffn) * (moe + sum_e probs_e * b2[e])  (fp32 out)
// ---------------------------------------------------------------------------
__global__ __launch_bounds__(256)
void kvnew_kernel(const float* __restrict__ kv, const bf16_t* __restrict__ moe,
                  const float* __restrict__ probs, const float* __restrict__ b2,
                  const float* __restrict__ gate_ffn, float* __restrict__ out) {
  const int idx = blockIdx.x * 256 + threadIdx.x;  // over B*TK*D/4
  const int row = idx >> 8;
  const int d = (idx & 255) * 4;
  const float sgf = 1.0f / (1.0f + __expf(-gate_ffn[0]));
  f32x4 pr = *(const f32x4*)&probs[row * 4];
  f32x4 acc = {};
#pragma unroll
  for (int e = 0; e < 4; ++e) {
    f32x4 b4 = *(const f32x4*)&b2[e * D_ + d];
    acc += b4 * pr[e];
  }
  bf16x4 mo = *(const bf16x4*)&moe[(size_t)row * D_ + d];
  f32x4 kvv = *(const f32x4*)&kv[(size_t)row * D_ + d];
  f32x4 res;
#pragma unroll
  for (int c = 0; c < 4; ++c) res[c] = kvv[c] + sgf * ((float)mo[c] + acc[c]);
  *(f32x4*)&out[(size_t)row * D_ + d] = res;
}

// ---------------------------------------------------------------------------
extern "C" void kernel_launch(void* const* d_in, const int* in_sizes, int n_in,
                              void* d_out, int out_size, void* d_ws, size_t ws_size,
                              hipStream_t stream) {
  const float* q           = (const float*)d_in[0];
  const float* kv          = (const float*)d_in[1];
  const float* qn_w        = (const float*)d_in[2];
  const float* kva_w       = (const float*)d_in[3];
  const float* kvi_w       = (const float*)d_in[4];
  const float* dn_w        = (const float*)d_in[5];
  const float* fn_w        = (const float*)d_in[6];
  const float* Wq          = (const float*)d_in[7];
  const float* bq          = (const float*)d_in[8];
  const float* Wk          = (const float*)d_in[9];
  const float* bk          = (const float*)d_in[10];
  const float* Wv          = (const float*)d_in[11];
  const float* bv          = (const float*)d_in[12];
  const float* Wo          = (const float*)d_in[13];
  const float* bo          = (const float*)d_in[14];
  const float* active_bias = (const float*)d_in[15];
  const float* inactive_b  = (const float*)d_in[16];
  const float* log_temp    = (const float*)d_in[17];
  const float* gate_attn   = (const float*)d_in[18];
  const float* gate_ffn    = (const float*)d_in[19];
  const float* Wr          = (const float*)d_in[20];
  const float* br          = (const float*)d_in[21];
  const float* W1          = (const float*)d_in[22];
  const float* b1          = (const float*)d_in[23];
  const float* W2          = (const float*)d_in[24];
  const float* b2          = (const float*)d_in[25];
  // d_in[26] kv_mask: unused in reference forward
  const int*   n_act       = (const int*)d_in[27];

  char* ws = (char*)d_ws;
  size_t off = 0;
  auto alloc = [&](size_t bytes) -> char* {
    char* p = ws + off;
    off = (off + bytes + 255) & ~(size_t)255;
    return p;
  };

  bf16_t* wqT  = (bf16_t*)alloc((size_t)D_ * D_ * 2);
  bf16_t* wkT  = (bf16_t*)alloc((size_t)D_ * D_ * 2);
  bf16_t* wvT  = (bf16_t*)alloc((size_t)D_ * D_ * 2);
  bf16_t* woT  = (bf16_t*)alloc((size_t)D_ * D_ * 2);
  bf16_t* w1T  = (bf16_t*)alloc((size_t)256 * D_ * 2);      // (NE*2HID, D)
  bf16_t* w2T  = (bf16_t*)alloc((size_t)D_ * 128 * 2);      // (D, NE*HID)
  bf16_t* kvb  = (bf16_t*)alloc((size_t)B_ * TK_ * D_ * 2);
  bf16_t* xn   = (bf16_t*)alloc((size_t)B_ * TK_ * D_ * 2);
  bf16_t* qn   = (bf16_t*)alloc((size_t)B_ * TQ_ * D_ * 2);
  bf16_t* qp   = (bf16_t*)alloc((size_t)B_ * TQ_ * D_ * 2);
  bf16_t* kbuf = (bf16_t*)alloc((size_t)B_ * TK_ * D_ * 2);
  bf16_t* vbuf = (bf16_t*)alloc((size_t)B_ * TK_ * D_ * 2);
  float*  probs = (float*)alloc((size_t)B_ * TK_ * NE_ * 4);
  // reuse (after last consumer):
  bf16_t* attno = qn;    // qn consumed by qp GEMM before attention writes
  bf16_t* proj  = qp;    // qp consumed by attention before proj GEMM writes
  bf16_t* hbuf  = vbuf;  // vbuf consumed by attention before h GEMM writes
  bf16_t* a2buf = kbuf;  // kbuf consumed by attention before act writes
  bf16_t* moe   = kvb;   // kvb consumed by k/v GEMMs before moe GEMM writes
  (void)ws_size; (void)in_sizes; (void)n_in; (void)out_size;

  float* q_new_out  = (float*)d_out;
  float* kv_new_out = (float*)d_out + (size_t)B_ * TQ_ * D_;

  dim3 tb(32, 8);
  // weight convert+transpose to bf16 (N,K)
  transpose_conv_kernel<<<dim3(32, 32, 1), tb, 0, stream>>>(Wq, wqT, D_, D_, 0, D_, 0, 0);
  transpose_conv_kernel<<<dim3(32, 32, 1), tb, 0, stream>>>(Wk, wkT, D_, D_, 0, D_, 0, 0);
  transpose_conv_kernel<<<dim3(32, 32, 1), tb, 0, stream>>>(Wv, wvT, D_, D_, 0, D_, 0, 0);
  transpose_conv_kernel<<<dim3(32, 32, 1), tb, 0, stream>>>(Wo, woT, D_, D_, 0, D_, 0, 0);
  // W1 (NE,D,2HID) -> w1T[(e*64+hh)][d]
  transpose_conv_kernel<<<dim3(2, 32, 4), tb, 0, stream>>>(W1, w1T, D_, 64, D_ * 64, D_, 64, 0);
  // W2 (NE,HID,D) -> w2T[d][e*32+hh]
  transpose_conv_kernel<<<dim3(32, 1, 4), tb, 0, stream>>>(W2, w2T, 32, D_, 32 * D_, 128, 0, 32);

  // norms
  rms_kv_kernel<<<B_ * TK_, 256, 0, stream>>>(kv, kva_w, kvi_w, fn_w, active_bias,
                                              inactive_b, n_act, kvb, xn);
  rms_q_kernel<<<B_ * TQ_, 256, 0, stream>>>(q, qn_w, qn);

  // projections
  gemm_tn<1><<<dim3(B_ * TQ_ / 128, D_ / 128), 256, 0, stream>>>(qn, wqT, bq, qp, B_ * TQ_, D_, D_);
  gemm_tn<1><<<dim3(B_ * TK_ / 128, D_ / 128), 256, 0, stream>>>(kvb, wkT, bk, kbuf, B_ * TK_, D_, D_);
  gemm_tn<1><<<dim3(B_ * TK_ / 128, D_ / 128), 256, 0, stream>>>(kvb, wvT, bv, vbuf, B_ * TK_, D_, D_);

  // attention
  attn_kernel<<<B_ * H_ * (TQ_ / 64), 256, 0, stream>>>(qp, kbuf, vbuf, attno, log_temp, n_act);

  // output projection + gated residual
  gemm_tn<1><<<dim3(B_ * TQ_ / 128, D_ / 128), 256, 0, stream>>>(attno, woT, bo, proj, B_ * TQ_, D_, D_);
  delta_qnew_kernel<<<B_ * TQ_, 256, 0, stream>>>(proj, dn_w, q, gate_attn, q_new_out);

  // MoE (decoupled from attention path by softmax shift-invariance)
  probs_kernel<<<B_ * TK_ / 4, 256, 0, stream>>>(xn, Wr, br, probs);
  gemm_tn<1><<<dim3(B_ * TK_ / 128, 256 / 128), 256, 0, stream>>>(xn, w1T, b1, hbuf, B_ * TK_, 256, D_);
  act_kernel<<<B_ * TK_ * 128 / 256, 256, 0, stream>>>(hbuf, probs, a2buf);
  gemm_tn<0><<<dim3(B_ * TK_ / 128, D_ / 128), 256, 0, stream>>>(a2buf, w2T, nullptr, moe, B_ * TK_, D_, 128);
  kvnew_kernel<<<B_ * TK_ * D_ / 4 / 256, 256, 0, stream>>>(kv, moe, probs, b2, gate_ffn, kv_new_out);
}

// Round 2
// 417.748 us; speedup vs baseline: 2.3491x; 2.3491x over previous
//
#include <hip/hip_runtime.h>
#include <hip/hip_bf16.h>
#include <stdint.h>

// ---------------------------------------------------------------------------
// TransformerBlock fused forward for MI355X (gfx950).
// Shapes (fixed): B=8 TQ=512 TK=2048 D=1024 H=16 HD=64 NE=4 HID=32 NA=512.
//
// Round 2: MFMA flash attention (was fp32 VALU, 763us/981us).
//  * V produced TRANSPOSED per (b,h): vt[(b*16+h)*64+d][t] via batched GEMM
//    so the PV B-operand stages linearly (same pattern as K).
//  * attn: 4 waves x 16 q-rows, 64-wide K/V tiles double-buffered via
//    global_load_lds w/ pre-swizzled source cols; swizzled ds_read_b128
//    fragments (bank-conflict-free); softmax on C-layout frags with
//    16-lane-group shfl reduces; P via per-wave swizzled LDS.
// ---------------------------------------------------------------------------

#define B_   8
#define TQ_  512
#define TK_  2048
#define D_   1024
#define H_   16
#define HD_  64
#define NE_  4
#define HID_ 32
#define EPSF 1e-6f

typedef __bf16 bf16_t;
typedef __bf16 bf16x8 __attribute__((ext_vector_type(8)));
typedef __bf16 bf16x4 __attribute__((ext_vector_type(4)));
typedef float  f32x4  __attribute__((ext_vector_type(4)));

typedef __attribute__((address_space(1))) void gvoid_t;
typedef __attribute__((address_space(3))) void lvoid_t;

__device__ __forceinline__ void gld_lds16(const void* g, void* l) {
  // async global->LDS, 16B per lane; LDS dest is wave-uniform base + lane*16
  __builtin_amdgcn_global_load_lds((gvoid_t*)g, (lvoid_t*)l, 16, 0, 0);
}

// ---------------------------------------------------------------------------
// Weight convert + transpose: out[(c + bz*ob_row)*out_rstride + bz*ob_col + r]
//   = (bf16) in[bz*in_bstride + r*C + c]
// ---------------------------------------------------------------------------
__global__ void transpose_conv_kernel(const float* __restrict__ in, bf16_t* __restrict__ out,
                                      int R, int C, int in_bstride,
                                      int out_rstride, int ob_row, int ob_col) {
  __shared__ float tile[32][33];
  const int bz = blockIdx.z;
  const int rb = blockIdx.y * 32, cb = blockIdx.x * 32;
  const int txi = threadIdx.x, tyi = threadIdx.y;
  const float* inp = in + (size_t)bz * in_bstride;
#pragma unroll
  for (int i = 0; i < 32; i += 8) {
    const int r = rb + tyi + i, c = cb + txi;
    if (r < R && c < C) tile[tyi + i][txi] = inp[(size_t)r * C + c];
  }
  __syncthreads();
#pragma unroll
  for (int i = 0; i < 32; i += 8) {
    const int orow = cb + tyi + i;   // original col
    const int ocol = rb + txi;       // original row
    if (orow < C && ocol < R)
      out[(size_t)(orow + bz * ob_row) * out_rstride + bz * ob_col + ocol] =
          (bf16_t)tile[txi][tyi + i];
  }
}

// ---------------------------------------------------------------------------
// Block-wide (256 thr) sum reduce
// ---------------------------------------------------------------------------
__device__ __forceinline__ float block_rsum(float v, float* red) {
  v += __shfl_xor(v, 1);  v += __shfl_xor(v, 2);  v += __shfl_xor(v, 4);
  v += __shfl_xor(v, 8);  v += __shfl_xor(v, 16); v += __shfl_xor(v, 32);
  const int tid = threadIdx.x;
  if ((tid & 63) == 0) red[tid >> 6] = v;
  __syncthreads();
  return red[0] + red[1] + red[2] + red[3];
}

// ---------------------------------------------------------------------------
// RMSNorm of kv -> kv_b (seg weights+bias) and x=rmsnorm(kv,fn_w), one pass.
// ---------------------------------------------------------------------------
__global__ __launch_bounds__(256)
void rms_kv_kernel(const float* __restrict__ kv, const float* __restrict__ kva_w,
                   const float* __restrict__ kvi_w, const float* __restrict__ fn_w,
                   const float* __restrict__ ab, const float* __restrict__ ib,
                   const int* __restrict__ n_act,
                   bf16_t* __restrict__ kvb, bf16_t* __restrict__ xn) {
  __shared__ float red[4];
  const int row = blockIdx.x;
  const int t = row & (TK_ - 1);
  const int tid = threadIdx.x;
  const float* src = kv + (size_t)row * D_;
  f32x4 v = ((const f32x4*)src)[tid];
  float ss = v[0]*v[0] + v[1]*v[1] + v[2]*v[2] + v[3]*v[3];
  ss = block_rsum(ss, red);
  const float rs = rsqrtf(ss * (1.0f / D_) + EPSF);
  const int Na = n_act[0];
  const float* wsel = (t < Na) ? kva_w : kvi_w;
  const float* bsel = (t < Na) ? ab : ib;
  const int d = tid * 4;
  f32x4 wv = *(const f32x4*)(wsel + d);
  f32x4 bv = *(const f32x4*)(bsel + d);
  f32x4 fv = *(const f32x4*)(fn_w + d);
  bf16x4 o0, o1;
#pragma unroll
  for (int c = 0; c < 4; ++c) {
    const float xv = v[c] * rs;
    o0[c] = (bf16_t)(xv * wv[c] + bv[c]);
    o1[c] = (bf16_t)(xv * fv[c]);
  }
  *(bf16x4*)&kvb[(size_t)row * D_ + d] = o0;
  *(bf16x4*)&xn [(size_t)row * D_ + d] = o1;
}

__global__ __launch_bounds__(256)
void rms_q_kernel(const float* __restrict__ q, const float* __restrict__ qn_w,
                  bf16_t* __restrict__ qn) {
  __shared__ float red[4];
  const int row = blockIdx.x;
  const int tid = threadIdx.x;
  const float* src = q + (size_t)row * D_;
  f32x4 v = ((const f32x4*)src)[tid];
  float ss = v[0]*v[0] + v[1]*v[1] + v[2]*v[2] + v[3]*v[3];
  ss = block_rsum(ss, red);
  const float rs = rsqrtf(ss * (1.0f / D_) + EPSF);
  const int d = tid * 4;
  f32x4 wv = *(const f32x4*)(qn_w + d);
  bf16x4 o0;
#pragma unroll
  for (int c = 0; c < 4; ++c) o0[c] = (bf16_t)(v[c] * rs * wv[c]);
  *(bf16x4*)&qn[(size_t)row * D_ + d] = o0;
}

// ---------------------------------------------------------------------------
// bf16 MFMA GEMM: C(M,N) = A(M,K) @ Wt(N,K)^T (+ bias[N]), bf16 out, f32 acc.
// 128x128 tile, BK=32, 256 thr (4 waves 2x2), global_load_lds x16.
// ---------------------------------------------------------------------------
template<int HAS_BIAS>
__global__ __launch_bounds__(256)
void gemm_tn(const bf16_t* __restrict__ A, const bf16_t* __restrict__ Wt,
             const float* __restrict__ bias, bf16_t* __restrict__ C,
             int M, int N, int K) {
  __shared__ alignas(16) bf16_t As[128 * 32];
  __shared__ alignas(16) bf16_t Bs[128 * 32];
  const int tid = threadIdx.x;
  const int lane = tid & 63;
  const int w = tid >> 6;
  const int wr = w >> 1, wc = w & 1;
  const int m0 = blockIdx.x * 128;
  const int n0 = blockIdx.y * 128;

  f32x4 acc[4][4] = {};

  const int eidx = tid * 8;
  const int srow = eidx >> 5;
  const int scol = eidx & 31;
  const bf16_t* ga = A  + (size_t)(m0 + srow) * K + scol;
  const bf16_t* gb = Wt + (size_t)(n0 + srow) * K + scol;
  bf16_t* la0 = &As[tid * 8];
  bf16_t* la1 = &As[2048 + tid * 8];
  bf16_t* lb0 = &Bs[tid * 8];
  bf16_t* lb1 = &Bs[2048 + tid * 8];
  const size_t rstep = (size_t)64 * K;

  const int kb = (lane >> 4) * 8;
  const int ar  = (wr * 64 + (lane & 15)) * 32 + kb;
  const int br2 = (wc * 64 + (lane & 15)) * 32 + kb;

  for (int k0 = 0; k0 < K; k0 += 32) {
    gld_lds16(ga + k0,         la0);
    gld_lds16(ga + k0 + rstep, la1);
    gld_lds16(gb + k0,         lb0);
    gld_lds16(gb + k0 + rstep, lb1);
    __syncthreads();
    bf16x8 af[4], bfr[4];
#pragma unroll
    for (int i = 0; i < 4; ++i) af[i]  = *(const bf16x8*)&As[ar  + i * 512];
#pragma unroll
    for (int j = 0; j < 4; ++j) bfr[j] = *(const bf16x8*)&Bs[br2 + j * 512];
#pragma unroll
    for (int i = 0; i < 4; ++i)
#pragma unroll
      for (int j = 0; j < 4; ++j)
        acc[i][j] = __builtin_amdgcn_mfma_f32_16x16x32_bf16(af[i], bfr[j], acc[i][j], 0, 0, 0);
    __syncthreads();
  }

  // C/D layout: col = lane&15, row = (lane>>4)*4 + reg
  const int row0 = m0 + wr * 64 + ((lane >> 4) << 2);
  const int col0 = n0 + wc * 64 + (lane & 15);
#pragma unroll
  for (int j = 0; j < 4; ++j) {
    const int cc = col0 + j * 16;
    const float bv = HAS_BIAS ? bias[cc] : 0.0f;
#pragma unroll
    for (int i = 0; i < 4; ++i) {
      const int rr = row0 + i * 16;
#pragma unroll
      for (int r = 0; r < 4; ++r)
        C[(size_t)(rr + r) * N + cc] = (bf16_t)(acc[i][j][r] + bv);
    }
  }
}

// ---------------------------------------------------------------------------
// Batched transposed-output V GEMM:
//   C_b(n, t) = sum_k wvT[n][k] * kvb_b[t][k] + bv[n]   (bias per ROW)
//   C_b = vt + b*1024*2048, n=(h*64+d), M=1024, N=2048, K=1024, grid.z=b
// ---------------------------------------------------------------------------
__global__ __launch_bounds__(256)
void gemm_vt(const bf16_t* __restrict__ A, const bf16_t* __restrict__ Wt0,
             const float* __restrict__ bias, bf16_t* __restrict__ C0) {
  __shared__ alignas(16) bf16_t As[128 * 32];
  __shared__ alignas(16) bf16_t Bs[128 * 32];
  const int K = D_, N = TK_;
  const bf16_t* Wt = Wt0 + (size_t)blockIdx.z * TK_ * D_;
  bf16_t* C = C0 + (size_t)blockIdx.z * D_ * TK_;
  const int tid = threadIdx.x;
  const int lane = tid & 63;
  const int w = tid >> 6;
  const int wr = w >> 1, wc = w & 1;
  const int m0 = blockIdx.x * 128;
  const int n0 = blockIdx.y * 128;

  f32x4 acc[4][4] = {};

  const int eidx = tid * 8;
  const int srow = eidx >> 5;
  const int scol = eidx & 31;
  const bf16_t* ga = A  + (size_t)(m0 + srow) * K + scol;
  const bf16_t* gb = Wt + (size_t)(n0 + srow) * K + scol;
  bf16_t* la0 = &As[tid * 8];
  bf16_t* la1 = &As[2048 + tid * 8];
  bf16_t* lb0 = &Bs[tid * 8];
  bf16_t* lb1 = &Bs[2048 + tid * 8];
  const size_t rstep = (size_t)64 * K;

  const int kb = (lane >> 4) * 8;
  const int ar  = (wr * 64 + (lane & 15)) * 32 + kb;
  const int br2 = (wc * 64 + (lane & 15)) * 32 + kb;

  for (int k0 = 0; k0 < K; k0 += 32) {
    gld_lds16(ga + k0,         la0);
    gld_lds16(ga + k0 + rstep, la1);
    gld_lds16(gb + k0,         lb0);
    gld_lds16(gb + k0 + rstep, lb1);
    __syncthreads();
    bf16x8 af[4], bfr[4];
#pragma unroll
    for (int i = 0; i < 4; ++i) af[i]  = *(const bf16x8*)&As[ar  + i * 512];
#pragma unroll
    for (int j = 0; j < 4; ++j) bfr[j] = *(const bf16x8*)&Bs[br2 + j * 512];
#pragma unroll
    for (int i = 0; i < 4; ++i)
#pragma unroll
      for (int j = 0; j < 4; ++j)
        acc[i][j] = __builtin_amdgcn_mfma_f32_16x16x32_bf16(af[i], bfr[j], acc[i][j], 0, 0, 0);
    __syncthreads();
  }

  const int row0 = m0 + wr * 64 + ((lane >> 4) << 2);
  const int col0 = n0 + wc * 64 + (lane & 15);
#pragma unroll
  for (int i = 0; i < 4; ++i) {
    const int rr = row0 + i * 16;
#pragma unroll
    for (int r = 0; r < 4; ++r) {
      const float bv = bias[rr + r];
#pragma unroll
      for (int j = 0; j < 4; ++j)
        C[(size_t)(rr + r) * N + col0 + j * 16] = (bf16_t)(acc[i][j][r] + bv);
    }
  }
}

// ---------------------------------------------------------------------------
// MFMA flash attention, two segments.
// Block = 256 thr (4 waves) handles (b, h, 64 q-rows); wave w: rows w*16..+16.
// K tile: Ks[kpos][d] bf16 64x64; V tile: Vs[d][kpos] (from vt global).
// Both staged via global_load_lds with source-chunk XOR pre-swizzle
// (chunk ^= row&7, 8-elem chunks) -> swizzled ds_read_b128 is conflict-free.
// P: per-wave 16x64 swizzled LDS round-trip (C-layout -> A-layout).
// ---------------------------------------------------------------------------
__global__ __launch_bounds__(256, 3)
void attn_mfma_kernel(const bf16_t* __restrict__ qp, const bf16_t* __restrict__ kb,
                      const bf16_t* __restrict__ vt, bf16_t* __restrict__ attno,
                      const float* __restrict__ log_temp, const int* __restrict__ n_act) {
  __shared__ alignas(16) bf16_t Ks[2][64 * 64];
  __shared__ alignas(16) bf16_t Vs[2][64 * 64];
  __shared__ alignas(16) bf16_t Ps[4][16 * 64];

  const int bidx = blockIdx.x;
  const int qt = bidx & 7;
  const int h  = (bidx >> 3) & 15;
  const int b  = bidx >> 7;
  const int tid = threadIdx.x;
  const int lane = tid & 63;
  const int w = tid >> 6;
  const int lane15 = lane & 15, lgrp = lane >> 4, l7 = lane & 7;
  const int Na = n_act[0];
  float temp = __expf(log_temp[0]);
  temp = fminf(fmaxf(temp, 0.1f), 10.0f);
  const float sc = 1.0f / (64.0f * temp);   // folded into exp args
  const int q0 = qt * 64;

  // Q fragments (A-operand): row = lane15, k(d) = lgrp*8 (+32)
  const bf16_t* qsrc = qp + (size_t)(b * TQ_ + q0 + w * 16 + lane15) * D_ + h * 64 + lgrp * 8;
  const bf16x8 qf0 = *(const bf16x8*)qsrc;
  const bf16x8 qf1 = *(const bf16x8*)(qsrc + 32);

  // staging source addresses (pre-swizzled chunk)
  const int srow = tid >> 3;                         // tile row 0..31 (pass0)
  const int schunk = (tid & 7) ^ (srow & 7);         // source chunk
  const bf16_t* ksrc = kb + (size_t)(b * TK_ + srow) * D_ + h * 64 + schunk * 8;
  const bf16_t* vsrc = vt + ((size_t)(b * 16 + h) * 64 + srow) * TK_ + schunk * 8;

  f32x4 o[4] = {};
  f32x4 outa[4] = {};
  float m_s[4], l_s[4];
#pragma unroll
  for (int r = 0; r < 4; ++r) { m_s[r] = -1e30f; l_s[r] = 0.f; }

  const float inv_sa = rsqrtf((float)(Na > 1 ? Na : 1));
  const int Ni = TK_ - Na;
  const float inv_si = rsqrtf((float)(Ni > 1 ? Ni : 1));

  // prologue: stage tile 0 into buf 0
  gld_lds16(ksrc,               &Ks[0][tid * 8]);
  gld_lds16(ksrc + 32 * D_,     &Ks[0][2048 + tid * 8]);
  gld_lds16(vsrc,               &Vs[0][tid * 8]);
  gld_lds16(vsrc + 32 * TK_,    &Vs[0][2048 + tid * 8]);

  for (int t = 0; t < TK_ / 64; ++t) {
    const int cur = t & 1;
    __syncthreads();   // staging of tile t complete; prev compute done
    if (t + 1 < TK_ / 64) {
      const int nb = cur ^ 1;
      const bf16_t* kN = ksrc + (size_t)(t + 1) * 64 * D_;
      const bf16_t* vN = vsrc + (size_t)(t + 1) * 64;
      gld_lds16(kN,            &Ks[nb][tid * 8]);
      gld_lds16(kN + 32 * D_,  &Ks[nb][2048 + tid * 8]);
      gld_lds16(vN,            &Vs[nb][tid * 8]);
      gld_lds16(vN + 32 * TK_, &Vs[nb][2048 + tid * 8]);
    }

    // ---- S = Q @ K^T : 8 MFMAs; sacc[cf] C-layout (col kpos, row q) ----
    f32x4 sacc[4];
#pragma unroll
    for (int cf = 0; cf < 4; ++cf) {
      const int krow = (cf * 16 + lane15) * 64;
      const bf16x8 kf0 = *(const bf16x8*)&Ks[cur][krow + ((lgrp ^ l7) << 3)];
      const bf16x8 kf1 = *(const bf16x8*)&Ks[cur][krow + (((lgrp + 4) ^ l7) << 3)];
      f32x4 s = {};
      s = __builtin_amdgcn_mfma_f32_16x16x32_bf16(qf0, kf0, s, 0, 0, 0);
      s = __builtin_amdgcn_mfma_f32_16x16x32_bf16(qf1, kf1, s, 0, 0, 0);
      sacc[cf] = s;
    }

    // ---- online softmax (rows live in regs r, 16-lane-group reduces) ----
    float fr[4];
#pragma unroll
    for (int r = 0; r < 4; ++r) {
      float mt = fmaxf(fmaxf(sacc[0][r], sacc[1][r]), fmaxf(sacc[2][r], sacc[3][r]));
      mt = fmaxf(mt, __shfl_xor(mt, 1));
      mt = fmaxf(mt, __shfl_xor(mt, 2));
      mt = fmaxf(mt, __shfl_xor(mt, 4));
      mt = fmaxf(mt, __shfl_xor(mt, 8));
      const float mnew = fmaxf(m_s[r], mt);
      fr[r] = __expf((m_s[r] - mnew) * sc);
      m_s[r] = mnew;
      float ps = 0.f;
#pragma unroll
      for (int cf = 0; cf < 4; ++cf) {
        const float p = __expf((sacc[cf][r] - mnew) * sc);
        sacc[cf][r] = p;
        ps += p;
      }
      ps += __shfl_xor(ps, 1); ps += __shfl_xor(ps, 2);
      ps += __shfl_xor(ps, 4); ps += __shfl_xor(ps, 8);
      l_s[r] = l_s[r] * fr[r] + ps;
    }
    const f32x4 fv4 = { fr[0], fr[1], fr[2], fr[3] };
#pragma unroll
    for (int df = 0; df < 4; ++df) o[df] *= fv4;

    // ---- P: C-layout regs -> per-wave swizzled LDS (bf16) ----
#pragma unroll
    for (int cf = 0; cf < 4; ++cf) {
      const int kp = cf * 16 + lane15;
      const int kcb = kp >> 3, kin = kp & 7;
#pragma unroll
      for (int r = 0; r < 4; ++r) {
        const int ql = lgrp * 4 + r;
        Ps[w][ql * 64 + ((kcb ^ (ql & 7)) << 3) + kin] = (bf16_t)sacc[cf][r];
      }
    }

    // ---- O += P @ V : A-frags from Ps, B-frags from Vs; 8 MFMAs ----
    {
      const int prow = lane15 * 64;
      const bf16x8 pa0 = *(const bf16x8*)&Ps[w][prow + ((lgrp ^ l7) << 3)];
      const bf16x8 pa1 = *(const bf16x8*)&Ps[w][prow + (((lgrp + 4) ^ l7) << 3)];
#pragma unroll
      for (int df = 0; df < 4; ++df) {
        const int vrow = (df * 16 + lane15) * 64;
        const bf16x8 vf0 = *(const bf16x8*)&Vs[cur][vrow + ((lgrp ^ l7) << 3)];
        const bf16x8 vf1 = *(const bf16x8*)&Vs[cur][vrow + (((lgrp + 4) ^ l7) << 3)];
        o[df] = __builtin_amdgcn_mfma_f32_16x16x32_bf16(pa0, vf0, o[df], 0, 0, 0);
        o[df] = __builtin_amdgcn_mfma_f32_16x16x32_bf16(pa1, vf1, o[df], 0, 0, 0);
      }
    }

    // ---- segment finalize ----
    const bool endA = ((t + 1) * 64 == Na);
    const bool endI = (t == TK_ / 64 - 1);
    if (endA || endI) {
      const float ssc = endA ? inv_sa : -inv_si;
      f32x4 iv;
#pragma unroll
      for (int r = 0; r < 4; ++r) iv[r] = ssc / l_s[r];
#pragma unroll
      for (int df = 0; df < 4; ++df) { outa[df] += o[df] * iv; o[df] = (f32x4){}; }
#pragma unroll
      for (int r = 0; r < 4; ++r) { m_s[r] = -1e30f; l_s[r] = 0.f; }
    }
  }

  // ---- write O (C-layout scatter, 16 lanes contiguous in d) ----
#pragma unroll
  for (int df = 0; df < 4; ++df)
#pragma unroll
    for (int r = 0; r < 4; ++r)
      attno[(size_t)(b * TQ_ + q0 + w * 16 + lgrp * 4 + r) * D_ + h * 64 + df * 16 + lane15] =
          (bf16_t)outa[df][r];
}

// ---------------------------------------------------------------------------
// delta = rmsnorm(proj, dn_w); q_new = q + sigmoid(gate_attn)*delta (fp32 out)
// ---------------------------------------------------------------------------
__global__ __launch_bounds__(256)
void delta_qnew_kernel(const bf16_t* __restrict__ proj, const float* __restrict__ dn_w,
                       const float* __restrict__ q, const float* __restrict__ gate_attn,
                       float* __restrict__ qnew) {
  __shared__ float red[4];
  const int row = blockIdx.x;
  const int tid = threadIdx.x;
  bf16x4 pv = *(const bf16x4*)(proj + (size_t)row * D_ + tid * 4);
  f32x4 v;
#pragma unroll
  for (int c = 0; c < 4; ++c) v[c] = (float)pv[c];
  float ss = v[0]*v[0] + v[1]*v[1] + v[2]*v[2] + v[3]*v[3];
  ss = block_rsum(ss, red);
  const float rs = rsqrtf(ss * (1.0f / D_) + EPSF);
  const float sga = 1.0f / (1.0f + __expf(-gate_attn[0]));
  const int d = tid * 4;
  f32x4 wv = *(const f32x4*)(dn_w + d);
  f32x4 qv = *(const f32x4*)(q + (size_t)row * D_ + d);
  f32x4 out;
#pragma unroll
  for (int c = 0; c < 4; ++c) out[c] = qv[c] + sga * (v[c] * rs * wv[c]);
  *(f32x4*)&qnew[(size_t)row * D_ + d] = out;
}

// ---------------------------------------------------------------------------
// probs = softmax(x @ Wr + br) over NE=4. (sim term is a softmax shift: dead.)
// ---------------------------------------------------------------------------
__global__ __launch_bounds__(256)
void probs_kernel(const bf16_t* __restrict__ xn, const float* __restrict__ Wr,
                  const float* __restrict__ br, float* __restrict__ probs) {
  const int tid = threadIdx.x;
  const int lane = tid & 63;
  const int row = blockIdx.x * 4 + (tid >> 6);
  const bf16_t* xrow = xn + (size_t)row * D_;
  float a0 = 0.f, a1 = 0.f, a2 = 0.f, a3 = 0.f;
  for (int it = 0; it < D_ / 64; ++it) {
    const int d = it * 64 + lane;
    const float xv = (float)xrow[d];
    const f32x4 w4 = *(const f32x4*)&Wr[d * 4];
    a0 += xv * w4[0]; a1 += xv * w4[1]; a2 += xv * w4[2]; a3 += xv * w4[3];
  }
#pragma unroll
  for (int m = 1; m <= 32; m <<= 1) {
    a0 += __shfl_xor(a0, m); a1 += __shfl_xor(a1, m);
    a2 += __shfl_xor(a2, m); a3 += __shfl_xor(a3, m);
  }
  a0 += br[0]; a1 += br[1]; a2 += br[2]; a3 += br[3];
  const float mx = fmaxf(fmaxf(a0, a1), fmaxf(a2, a3));
  const float e0 = __expf(a0 - mx), e1 = __expf(a1 - mx);
  const float e2 = __expf(a2 - mx), e3 = __expf(a3 - mx);
  const float inv = 1.0f / (e0 + e1 + e2 + e3);
  if (lane == 0) {
    f32x4 pr = { e0 * inv, e1 * inv, e2 * inv, e3 * inv };
    *(f32x4*)&probs[row * 4] = pr;
  }
}

// ---------------------------------------------------------------------------
// a2[row][e*32+hh] = probs[row][e]*xp*silu(g); xp=h[e*64+hh], g=h[e*64+32+hh]
// ---------------------------------------------------------------------------
__global__ __launch_bounds__(256)
void act_kernel(const bf16_t* __restrict__ hbuf, const float* __restrict__ probs,
                bf16_t* __restrict__ a2buf) {
  const int idx = blockIdx.x * 256 + threadIdx.x;  // B*TK*NE*HID
  const int row = idx >> 7;
  const int eh = idx & 127;
  const int e = eh >> 5, hh = eh & 31;
  const float xp = (float)hbuf[(size_t)row * 256 + e * 64 + hh];
  const float g  = (float)hbuf[(size_t)row * 256 + e * 64 + 32 + hh];
  const float sg = 1.0f / (1.0f + __expf(-g));
  a2buf[idx] = (bf16_t)(probs[row * 4 + e] * xp * g * sg);
}

// ---------------------------------------------------------------------------
// kv_new = kv + sigmoid(gate_ffn) * (moe + sum_e probs_e * b2[e]) (fp32 out)
// ---------------------------------------------------------------------------
__global__ __launch_bounds__(256)
void kvnew_kernel(const float* __restrict__ kv, const bf16_t* __restrict__ moe,
                  const float* __restrict__ probs, const float* __restrict__ b2,
                  const float* __restrict__ gate_ffn, float* __restrict__ out) {
  const int idx = blockIdx.x * 256 + threadIdx.x;  // over B*TK*D/4
  const int row = idx >> 8;
  const int d = (idx & 255) * 4;
  const float sgf = 1.0f / (1.0f + __expf(-gate_ffn[0]));
  f32x4 pr = *(const f32x4*)&probs[row * 4];
  f32x4 acc = {};
#pragma unroll
  for (int e = 0; e < 4; ++e) {
    f32x4 b4 = *(const f32x4*)&b2[e * D_ + d];
    acc += b4 * pr[e];
  }
  bf16x4 mo = *(const bf16x4*)&moe[(size_t)row * D_ + d];
  f32x4 kvv = *(const f32x4*)&kv[(size_t)row * D_ + d];
  f32x4 res;
#pragma unroll
  for (int c = 0; c < 4; ++c) res[c] = kvv[c] + sgf * ((float)mo[c] + acc[c]);
  *(f32x4*)&out[(size_t)row * D_ + d] = res;
}

// ---------------------------------------------------------------------------
extern "C" void kernel_launch(void* const* d_in, const int* in_sizes, int n_in,
                              void* d_out, int out_size, void* d_ws, size_t ws_size,
                              hipStream_t stream) {
  const float* q           = (const float*)d_in[0];
  const float* kv          = (const float*)d_in[1];
  const float* qn_w        = (const float*)d_in[2];
  const float* kva_w       = (const float*)d_in[3];
  const float* kvi_w       = (const float*)d_in[4];
  const float* dn_w        = (const float*)d_in[5];
  const float* fn_w        = (const float*)d_in[6];
  const float* Wq          = (const float*)d_in[7];
  const float* bq          = (const float*)d_in[8];
  const float* Wk          = (const float*)d_in[9];
  const float* bk          = (const float*)d_in[10];
  const float* Wv          = (const float*)d_in[11];
  const float* bv          = (const float*)d_in[12];
  const float* Wo          = (const float*)d_in[13];
  const float* bo          = (const float*)d_in[14];
  const float* active_bias = (const float*)d_in[15];
  const float* inactive_b  = (const float*)d_in[16];
  const float* log_temp    = (const float*)d_in[17];
  const float* gate_attn   = (const float*)d_in[18];
  const float* gate_ffn    = (const float*)d_in[19];
  const float* Wr          = (const float*)d_in[20];
  const float* br          = (const float*)d_in[21];
  const float* W1          = (const float*)d_in[22];
  const float* b1          = (const float*)d_in[23];
  const float* W2          = (const float*)d_in[24];
  const float* b2          = (const float*)d_in[25];
  // d_in[26] kv_mask: unused (all-true in reference forward)
  const int*   n_act       = (const int*)d_in[27];

  char* ws = (char*)d_ws;
  size_t off = 0;
  auto alloc = [&](size_t bytes) -> char* {
    char* p = ws + off;
    off = (off + bytes + 255) & ~(size_t)255;
    return p;
  };

  bf16_t* wqT  = (bf16_t*)alloc((size_t)D_ * D_ * 2);
  bf16_t* wkT  = (bf16_t*)alloc((size_t)D_ * D_ * 2);
  bf16_t* wvT  = (bf16_t*)alloc((size_t)D_ * D_ * 2);
  bf16_t* woT  = (bf16_t*)alloc((size_t)D_ * D_ * 2);
  bf16_t* w1T  = (bf16_t*)alloc((size_t)256 * D_ * 2);      // (NE*2HID, D)
  bf16_t* w2T  = (bf16_t*)alloc((size_t)D_ * 128 * 2);      // (D, NE*HID)
  bf16_t* kvb  = (bf16_t*)alloc((size_t)B_ * TK_ * D_ * 2);
  bf16_t* xn   = (bf16_t*)alloc((size_t)B_ * TK_ * D_ * 2);
  bf16_t* qn   = (bf16_t*)alloc((size_t)B_ * TQ_ * D_ * 2);
  bf16_t* qp   = (bf16_t*)alloc((size_t)B_ * TQ_ * D_ * 2);
  bf16_t* kbuf = (bf16_t*)alloc((size_t)B_ * TK_ * D_ * 2);
  bf16_t* vt   = (bf16_t*)alloc((size_t)B_ * D_ * TK_ * 2); // V transposed per (b,h)
  float*  probs = (float*)alloc((size_t)B_ * TK_ * NE_ * 4);
  // reuse (after last consumer):
  bf16_t* attno = qn;    // qn consumed by qp GEMM before attention writes
  bf16_t* proj  = qp;    // qp consumed by attention before proj GEMM writes
  bf16_t* hbuf  = vt;    // vt consumed by attention before h GEMM writes
  bf16_t* a2buf = kbuf;  // kbuf consumed by attention before act writes
  bf16_t* moe   = kvb;   // kvb consumed by k/vt GEMMs before moe GEMM writes
  (void)ws_size; (void)in_sizes; (void)n_in; (void)out_size;

  float* q_new_out  = (float*)d_out;
  float* kv_new_out = (float*)d_out + (size_t)B_ * TQ_ * D_;

  dim3 tb(32, 8);
  transpose_conv_kernel<<<dim3(32, 32, 1), tb, 0, stream>>>(Wq, wqT, D_, D_, 0, D_, 0, 0);
  transpose_conv_kernel<<<dim3(32, 32, 1), tb, 0, stream>>>(Wk, wkT, D_, D_, 0, D_, 0, 0);
  transpose_conv_kernel<<<dim3(32, 32, 1), tb, 0, stream>>>(Wv, wvT, D_, D_, 0, D_, 0, 0);
  transpose_conv_kernel<<<dim3(32, 32, 1), tb, 0, stream>>>(Wo, woT, D_, D_, 0, D_, 0, 0);
  transpose_conv_kernel<<<dim3(2, 32, 4), tb, 0, stream>>>(W1, w1T, D_, 64, D_ * 64, D_, 64, 0);
  transpose_conv_kernel<<<dim3(32, 1, 4), tb, 0, stream>>>(W2, w2T, 32, D_, 32 * D_, 128, 0, 32);

  rms_kv_kernel<<<B_ * TK_, 256, 0, stream>>>(kv, kva_w, kvi_w, fn_w, active_bias,
                                              inactive_b, n_act, kvb, xn);
  rms_q_kernel<<<B_ * TQ_, 256, 0, stream>>>(q, qn_w, qn);

  gemm_tn<1><<<dim3(B_ * TQ_ / 128, D_ / 128), 256, 0, stream>>>(qn, wqT, bq, qp, B_ * TQ_, D_, D_);
  gemm_tn<1><<<dim3(B_ * TK_ / 128, D_ / 128), 256, 0, stream>>>(kvb, wkT, bk, kbuf, B_ * TK_, D_, D_);
  // V, transposed output per (b,h): vt[(b*16+h)*64+d][t]
  gemm_vt<<<dim3(D_ / 128, TK_ / 128, B_), 256, 0, stream>>>(wvT, kvb, bv, vt);

  attn_mfma_kernel<<<B_ * H_ * (TQ_ / 64), 256, 0, stream>>>(qp, kbuf, vt, attno, log_temp, n_act);

  gemm_tn<1><<<dim3(B_ * TQ_ / 128, D_ / 128), 256, 0, stream>>>(attno, woT, bo, proj, B_ * TQ_, D_, D_);
  delta_qnew_kernel<<<B_ * TQ_, 256, 0, stream>>>(proj, dn_w, q, gate_attn, q_new_out);

  probs_kernel<<<B_ * TK_ / 4, 256, 0, stream>>>(xn, Wr, br, probs);
  gemm_tn<1><<<dim3(B_ * TK_ / 128, 256 / 128), 256, 0, stream>>>(xn, w1T, b1, hbuf, B_ * TK_, 256, D_);
  act_kernel<<<B_ * TK_ * 128 / 256, 256, 0, stream>>>(hbuf, probs, a2buf);
  gemm_tn<0><<<dim3(B_ * TK_ / 128, D_ / 128), 256, 0, stream>>>(a2buf, w2T, nullptr, moe, B_ * TK_, D_, 128);
  kvnew_kernel<<<B_ * TK_ * D_ / 4 / 256, 256, 0, stream>>>(kv, moe, probs, b2, gate_ffn, kv_new_out);
}

// Round 3
// 368.254 us; speedup vs baseline: 2.6648x; 1.1344x over previous
//
#include <hip/hip_runtime.h>
#include <hip/hip_bf16.h>
#include <stdint.h>

// ---------------------------------------------------------------------------
// TransformerBlock fused forward for MI355X (gfx950).
// Shapes (fixed): B=8 TQ=512 TK=2048 D=1024 H=16 HD=64 NE=4 HID=32 NA=512.
//
// Round 3:
//  * attn: no-max exp2 softmax (scores bounded -> m=0 exact by shift-invar),
//    lane-local l accumulation (zero shfl per tile), 8 waves/128 q-rows per
//    block (halves K/V refetch), XCD-grouped block swizzle.
//  * probs fused into rms_kv (fp32 x in regs; kills 32MB re-read).
//  * act+probs fused into h-GEMM epilogue ((c,c+32) share a thread).
//  * kv_new residual fused into moe-GEMM epilogue.
// ---------------------------------------------------------------------------

#define B_   8
#define TQ_  512
#define TK_  2048
#define D_   1024
#define H_   16
#define HD_  64
#define NE_  4
#define HID_ 32
#define EPSF 1e-6f
#define LOG2E 1.44269504f

typedef __bf16 bf16_t;
typedef __bf16 bf16x8 __attribute__((ext_vector_type(8)));
typedef __bf16 bf16x4 __attribute__((ext_vector_type(4)));
typedef float  f32x4  __attribute__((ext_vector_type(4)));

typedef __attribute__((address_space(1))) void gvoid_t;
typedef __attribute__((address_space(3))) void lvoid_t;

__device__ __forceinline__ void gld_lds16(const void* g, void* l) {
  __builtin_amdgcn_global_load_lds((gvoid_t*)g, (lvoid_t*)l, 16, 0, 0);
}

// ---------------------------------------------------------------------------
// Weight convert + transpose: out[(c + bz*ob_row)*out_rstride + bz*ob_col + r]
//   = (bf16) in[bz*in_bstride + r*C + c]
// ---------------------------------------------------------------------------
__global__ void transpose_conv_kernel(const float* __restrict__ in, bf16_t* __restrict__ out,
                                      int R, int C, int in_bstride,
                                      int out_rstride, int ob_row, int ob_col) {
  __shared__ float tile[32][33];
  const int bz = blockIdx.z;
  const int rb = blockIdx.y * 32, cb = blockIdx.x * 32;
  const int txi = threadIdx.x, tyi = threadIdx.y;
  const float* inp = in + (size_t)bz * in_bstride;
#pragma unroll
  for (int i = 0; i < 32; i += 8) {
    const int r = rb + tyi + i, c = cb + txi;
    if (r < R && c < C) tile[tyi + i][txi] = inp[(size_t)r * C + c];
  }
  __syncthreads();
#pragma unroll
  for (int i = 0; i < 32; i += 8) {
    const int orow = cb + tyi + i;
    const int ocol = rb + txi;
    if (orow < C && ocol < R)
      out[(size_t)(orow + bz * ob_row) * out_rstride + bz * ob_col + ocol] =
          (bf16_t)tile[txi][tyi + i];
  }
}

__device__ __forceinline__ float block_rsum(float v, float* red) {
  v += __shfl_xor(v, 1);  v += __shfl_xor(v, 2);  v += __shfl_xor(v, 4);
  v += __shfl_xor(v, 8);  v += __shfl_xor(v, 16); v += __shfl_xor(v, 32);
  const int tid = threadIdx.x;
  if ((tid & 63) == 0) red[tid >> 6] = v;
  __syncthreads();
  return red[0] + red[1] + red[2] + red[3];
}

// ---------------------------------------------------------------------------
// RMSNorm of kv -> kvb (seg weights+bias), xn = rmsnorm(kv,fn_w), AND
// probs = softmax(x @ Wr + br)  (sim term is a softmax shift: dead).
// ---------------------------------------------------------------------------
__global__ __launch_bounds__(256)
void rms_kv_kernel(const float* __restrict__ kv, const float* __restrict__ kva_w,
                   const float* __restrict__ kvi_w, const float* __restrict__ fn_w,
                   const float* __restrict__ ab, const float* __restrict__ ib,
                   const int* __restrict__ n_act, const float* __restrict__ Wr,
                   const float* __restrict__ br,
                   bf16_t* __restrict__ kvb, bf16_t* __restrict__ xn,
                   float* __restrict__ probs) {
  __shared__ float red[4];
  __shared__ f32x4 pred[4];
  const int row = blockIdx.x;
  const int t = row & (TK_ - 1);
  const int tid = threadIdx.x;
  const float* src = kv + (size_t)row * D_;
  f32x4 v = ((const f32x4*)src)[tid];
  float ss = v[0]*v[0] + v[1]*v[1] + v[2]*v[2] + v[3]*v[3];
  ss = block_rsum(ss, red);
  const float rs = rsqrtf(ss * (1.0f / D_) + EPSF);
  const int Na = n_act[0];
  const float* wsel = (t < Na) ? kva_w : kvi_w;
  const float* bsel = (t < Na) ? ab : ib;
  const int d = tid * 4;
  f32x4 wv = *(const f32x4*)(wsel + d);
  f32x4 bv = *(const f32x4*)(bsel + d);
  f32x4 fv = *(const f32x4*)(fn_w + d);
  bf16x4 o0, o1;
  f32x4 p4 = {};
#pragma unroll
  for (int c = 0; c < 4; ++c) {
    const float xv = v[c] * rs;
    const float xf = xv * fv[c];
    o0[c] = (bf16_t)(xv * wv[c] + bv[c]);
    o1[c] = (bf16_t)xf;
    const f32x4 w4 = *(const f32x4*)&Wr[(d + c) * 4];
    p4 += w4 * xf;
  }
  *(bf16x4*)&kvb[(size_t)row * D_ + d] = o0;
  *(bf16x4*)&xn [(size_t)row * D_ + d] = o1;
  // reduce router logits
#pragma unroll
  for (int m = 1; m <= 32; m <<= 1) {
    p4[0] += __shfl_xor(p4[0], m); p4[1] += __shfl_xor(p4[1], m);
    p4[2] += __shfl_xor(p4[2], m); p4[3] += __shfl_xor(p4[3], m);
  }
  if ((tid & 63) == 0) pred[tid >> 6] = p4;
  __syncthreads();
  if (tid == 0) {
    f32x4 s = pred[0] + pred[1] + pred[2] + pred[3];
    s[0] += br[0]; s[1] += br[1]; s[2] += br[2]; s[3] += br[3];
    const float mx = fmaxf(fmaxf(s[0], s[1]), fmaxf(s[2], s[3]));
    const float e0 = __expf(s[0] - mx), e1 = __expf(s[1] - mx);
    const float e2 = __expf(s[2] - mx), e3 = __expf(s[3] - mx);
    const float inv = 1.0f / (e0 + e1 + e2 + e3);
    f32x4 pr = { e0 * inv, e1 * inv, e2 * inv, e3 * inv };
    *(f32x4*)&probs[row * 4] = pr;
  }
}

__global__ __launch_bounds__(256)
void rms_q_kernel(const float* __restrict__ q, const float* __restrict__ qn_w,
                  bf16_t* __restrict__ qn) {
  __shared__ float red[4];
  const int row = blockIdx.x;
  const int tid = threadIdx.x;
  const float* src = q + (size_t)row * D_;
  f32x4 v = ((const f32x4*)src)[tid];
  float ss = v[0]*v[0] + v[1]*v[1] + v[2]*v[2] + v[3]*v[3];
  ss = block_rsum(ss, red);
  const float rs = rsqrtf(ss * (1.0f / D_) + EPSF);
  const int d = tid * 4;
  f32x4 wv = *(const f32x4*)(qn_w + d);
  bf16x4 o0;
#pragma unroll
  for (int c = 0; c < 4; ++c) o0[c] = (bf16_t)(v[c] * rs * wv[c]);
  *(bf16x4*)&qn[(size_t)row * D_ + d] = o0;
}

// ---------------------------------------------------------------------------
// bf16 MFMA GEMM core: C(M,N) = A(M,K) @ Wt(N,K)^T (+bias), 128x128, BK=32.
// ---------------------------------------------------------------------------
template<int HAS_BIAS>
__global__ __launch_bounds__(256)
void gemm_tn(const bf16_t* __restrict__ A, const bf16_t* __restrict__ Wt,
             const float* __restrict__ bias, bf16_t* __restrict__ C,
             int M, int N, int K) {
  __shared__ alignas(16) bf16_t As[128 * 32];
  __shared__ alignas(16) bf16_t Bs[128 * 32];
  const int tid = threadIdx.x;
  const int lane = tid & 63;
  const int w = tid >> 6;
  const int wr = w >> 1, wc = w & 1;
  const int m0 = blockIdx.x * 128;
  const int n0 = blockIdx.y * 128;

  f32x4 acc[4][4] = {};

  const int eidx = tid * 8;
  const int srow = eidx >> 5;
  const int scol = eidx & 31;
  const bf16_t* ga = A  + (size_t)(m0 + srow) * K + scol;
  const bf16_t* gb = Wt + (size_t)(n0 + srow) * K + scol;
  bf16_t* la0 = &As[tid * 8];
  bf16_t* la1 = &As[2048 + tid * 8];
  bf16_t* lb0 = &Bs[tid * 8];
  bf16_t* lb1 = &Bs[2048 + tid * 8];
  const size_t rstep = (size_t)64 * K;

  const int kb = (lane >> 4) * 8;
  const int ar  = (wr * 64 + (lane & 15)) * 32 + kb;
  const int br2 = (wc * 64 + (lane & 15)) * 32 + kb;

  for (int k0 = 0; k0 < K; k0 += 32) {
    gld_lds16(ga + k0,         la0);
    gld_lds16(ga + k0 + rstep, la1);
    gld_lds16(gb + k0,         lb0);
    gld_lds16(gb + k0 + rstep, lb1);
    __syncthreads();
    bf16x8 af[4], bfr[4];
#pragma unroll
    for (int i = 0; i < 4; ++i) af[i]  = *(const bf16x8*)&As[ar  + i * 512];
#pragma unroll
    for (int j = 0; j < 4; ++j) bfr[j] = *(const bf16x8*)&Bs[br2 + j * 512];
#pragma unroll
    for (int i = 0; i < 4; ++i)
#pragma unroll
      for (int j = 0; j < 4; ++j)
        acc[i][j] = __builtin_amdgcn_mfma_f32_16x16x32_bf16(af[i], bfr[j], acc[i][j], 0, 0, 0);
    __syncthreads();
  }

  const int row0 = m0 + wr * 64 + ((lane >> 4) << 2);
  const int col0 = n0 + wc * 64 + (lane & 15);
#pragma unroll
  for (int j = 0; j < 4; ++j) {
    const int cc = col0 + j * 16;
    const float bv = HAS_BIAS ? bias[cc] : 0.0f;
#pragma unroll
    for (int i = 0; i < 4; ++i) {
      const int rr = row0 + i * 16;
#pragma unroll
      for (int r = 0; r < 4; ++r)
        C[(size_t)(rr + r) * N + cc] = (bf16_t)(acc[i][j][r] + bv);
    }
  }
}

// ---------------------------------------------------------------------------
// Batched transposed-output V GEMM: vt_b(n=h*64+d, t) = wvT@kvb_b^T + bv[n]
// ---------------------------------------------------------------------------
__global__ __launch_bounds__(256)
void gemm_vt(const bf16_t* __restrict__ A, const bf16_t* __restrict__ Wt0,
             const float* __restrict__ bias, bf16_t* __restrict__ C0) {
  __shared__ alignas(16) bf16_t As[128 * 32];
  __shared__ alignas(16) bf16_t Bs[128 * 32];
  const int K = D_, N = TK_;
  const bf16_t* Wt = Wt0 + (size_t)blockIdx.z * TK_ * D_;
  bf16_t* C = C0 + (size_t)blockIdx.z * D_ * TK_;
  const int tid = threadIdx.x;
  const int lane = tid & 63;
  const int w = tid >> 6;
  const int wr = w >> 1, wc = w & 1;
  const int m0 = blockIdx.x * 128;
  const int n0 = blockIdx.y * 128;

  f32x4 acc[4][4] = {};

  const int eidx = tid * 8;
  const int srow = eidx >> 5;
  const int scol = eidx & 31;
  const bf16_t* ga = A  + (size_t)(m0 + srow) * K + scol;
  const bf16_t* gb = Wt + (size_t)(n0 + srow) * K + scol;
  bf16_t* la0 = &As[tid * 8];
  bf16_t* la1 = &As[2048 + tid * 8];
  bf16_t* lb0 = &Bs[tid * 8];
  bf16_t* lb1 = &Bs[2048 + tid * 8];
  const size_t rstep = (size_t)64 * K;

  const int kb = (lane >> 4) * 8;
  const int ar  = (wr * 64 + (lane & 15)) * 32 + kb;
  const int br2 = (wc * 64 + (lane & 15)) * 32 + kb;

  for (int k0 = 0; k0 < K; k0 += 32) {
    gld_lds16(ga + k0,         la0);
    gld_lds16(ga + k0 + rstep, la1);
    gld_lds16(gb + k0,         lb0);
    gld_lds16(gb + k0 + rstep, lb1);
    __syncthreads();
    bf16x8 af[4], bfr[4];
#pragma unroll
    for (int i = 0; i < 4; ++i) af[i]  = *(const bf16x8*)&As[ar  + i * 512];
#pragma unroll
    for (int j = 0; j < 4; ++j) bfr[j] = *(const bf16x8*)&Bs[br2 + j * 512];
#pragma unroll
    for (int i = 0; i < 4; ++i)
#pragma unroll
      for (int j = 0; j < 4; ++j)
        acc[i][j] = __builtin_amdgcn_mfma_f32_16x16x32_bf16(af[i], bfr[j], acc[i][j], 0, 0, 0);
    __syncthreads();
  }

  const int row0 = m0 + wr * 64 + ((lane >> 4) << 2);
  const int col0 = n0 + wc * 64 + (lane & 15);
#pragma unroll
  for (int i = 0; i < 4; ++i) {
    const int rr = row0 + i * 16;
#pragma unroll
    for (int r = 0; r < 4; ++r) {
      const float bv = bias[rr + r];
#pragma unroll
      for (int j = 0; j < 4; ++j)
        C[(size_t)(rr + r) * N + col0 + j * 16] = (bf16_t)(acc[i][j][r] + bv);
    }
  }
}

// ---------------------------------------------------------------------------
// h-GEMM with fused bias + SiLU-gate + probs weighting.
// N=256 hidden cols -> writes a2 (M x 128): a2[row][e*32+hh] =
//   probs[row][e] * (h[e*64+hh]) * silu(h[e*64+32+hh]).
// Pairing: cols (c, c+32) are acc[i][j] and acc[i][j+2] of the same thread.
// ---------------------------------------------------------------------------
__global__ __launch_bounds__(256)
void gemm_h_act(const bf16_t* __restrict__ A, const bf16_t* __restrict__ Wt,
                const float* __restrict__ bias, const float* __restrict__ probs,
                bf16_t* __restrict__ a2) {
  __shared__ alignas(16) bf16_t As[128 * 32];
  __shared__ alignas(16) bf16_t Bs[128 * 32];
  const int K = D_;
  const int tid = threadIdx.x;
  const int lane = tid & 63;
  const int w = tid >> 6;
  const int wr = w >> 1, wc = w & 1;
  const int m0 = blockIdx.x * 128;
  const int n0 = blockIdx.y * 128;

  f32x4 acc[4][4] = {};

  const int eidx = tid * 8;
  const int srow = eidx >> 5;
  const int scol = eidx & 31;
  const bf16_t* ga = A  + (size_t)(m0 + srow) * K + scol;
  const bf16_t* gb = Wt + (size_t)(n0 + srow) * K + scol;
  bf16_t* la0 = &As[tid * 8];
  bf16_t* la1 = &As[2048 + tid * 8];
  bf16_t* lb0 = &Bs[tid * 8];
  bf16_t* lb1 = &Bs[2048 + tid * 8];
  const size_t rstep = (size_t)64 * K;

  const int kb = (lane >> 4) * 8;
  const int ar  = (wr * 64 + (lane & 15)) * 32 + kb;
  const int br2 = (wc * 64 + (lane & 15)) * 32 + kb;

  for (int k0 = 0; k0 < K; k0 += 32) {
    gld_lds16(ga + k0,         la0);
    gld_lds16(ga + k0 + rstep, la1);
    gld_lds16(gb + k0,         lb0);
    gld_lds16(gb + k0 + rstep, lb1);
    __syncthreads();
    bf16x8 af[4], bfr[4];
#pragma unroll
    for (int i = 0; i < 4; ++i) af[i]  = *(const bf16x8*)&As[ar  + i * 512];
#pragma unroll
    for (int j = 0; j < 4; ++j) bfr[j] = *(const bf16x8*)&Bs[br2 + j * 512];
#pragma unroll
    for (int i = 0; i < 4; ++i)
#pragma unroll
      for (int j = 0; j < 4; ++j)
        acc[i][j] = __builtin_amdgcn_mfma_f32_16x16x32_bf16(af[i], bfr[j], acc[i][j], 0, 0, 0);
    __syncthreads();
  }

  const int row0 = m0 + wr * 64 + ((lane >> 4) << 2);
  const int hbase = n0 + wc * 64 + (lane & 15);       // hidden col for j=0
  const int e = hbase >> 6;                           // expert (j<2 keeps <64)
#pragma unroll
  for (int j = 0; j < 2; ++j) {
    const int ch = hbase + j * 16;                    // xp col; g col = ch+32
    const float bx = bias[ch], bg = bias[ch + 32];
    const int ac = (ch & 63) + e * 32;                // a2 col = e*32 + hh
#pragma unroll
    for (int i = 0; i < 4; ++i) {
      const int rr = row0 + i * 16;
#pragma unroll
      for (int r = 0; r < 4; ++r) {
        const float xp = acc[i][j][r] + bx;
        const float g  = acc[i][j + 2][r] + bg;
        const float sg = 1.0f / (1.0f + __expf(-g));
        const float pr = probs[(size_t)(rr + r) * 4 + e];
        a2[(size_t)(rr + r) * 128 + ac] = (bf16_t)(pr * xp * g * sg);
      }
    }
  }
}

// ---------------------------------------------------------------------------
// moe-GEMM (K=128) with fused kv_new epilogue:
//   out[row][col] = kv + sigmoid(gate_ffn)*(acc + sum_e probs_e*b2[e][col])
// ---------------------------------------------------------------------------
__global__ __launch_bounds__(256)
void gemm_moe_kvnew(const bf16_t* __restrict__ A, const bf16_t* __restrict__ Wt,
                    const float* __restrict__ kv, const float* __restrict__ probs,
                    const float* __restrict__ b2, const float* __restrict__ gate_ffn,
                    float* __restrict__ out) {
  __shared__ alignas(16) bf16_t As[128 * 32];
  __shared__ alignas(16) bf16_t Bs[128 * 32];
  const int K = 128, N = D_;
  const int tid = threadIdx.x;
  const int lane = tid & 63;
  const int w = tid >> 6;
  const int wr = w >> 1, wc = w & 1;
  const int m0 = blockIdx.x * 128;
  const int n0 = blockIdx.y * 128;

  f32x4 acc[4][4] = {};

  const int eidx = tid * 8;
  const int srow = eidx >> 5;
  const int scol = eidx & 31;
  const bf16_t* ga = A  + (size_t)(m0 + srow) * K + scol;
  const bf16_t* gb = Wt + (size_t)(n0 + srow) * K + scol;
  bf16_t* la0 = &As[tid * 8];
  bf16_t* la1 = &As[2048 + tid * 8];
  bf16_t* lb0 = &Bs[tid * 8];
  bf16_t* lb1 = &Bs[2048 + tid * 8];
  const size_t rstep = (size_t)64 * K;

  const int kb = (lane >> 4) * 8;
  const int ar  = (wr * 64 + (lane & 15)) * 32 + kb;
  const int br2 = (wc * 64 + (lane & 15)) * 32 + kb;

  for (int k0 = 0; k0 < K; k0 += 32) {
    gld_lds16(ga + k0,         la0);
    gld_lds16(ga + k0 + rstep, la1);
    gld_lds16(gb + k0,         lb0);
    gld_lds16(gb + k0 + rstep, lb1);
    __syncthreads();
    bf16x8 af[4], bfr[4];
#pragma unroll
    for (int i = 0; i < 4; ++i) af[i]  = *(const bf16x8*)&As[ar  + i * 512];
#pragma unroll
    for (int j = 0; j < 4; ++j) bfr[j] = *(const bf16x8*)&Bs[br2 + j * 512];
#pragma unroll
    for (int i = 0; i < 4; ++i)
#pragma unroll
      for (int j = 0; j < 4; ++j)
        acc[i][j] = __builtin_amdgcn_mfma_f32_16x16x32_bf16(af[i], bfr[j], acc[i][j], 0, 0, 0);
    __syncthreads();
  }

  const float sgf = 1.0f / (1.0f + __expf(-gate_ffn[0]));
  const int row0 = m0 + wr * 64 + ((lane >> 4) << 2);
  const int col0 = n0 + wc * 64 + (lane & 15);
#pragma unroll
  for (int j = 0; j < 4; ++j) {
    const int cc = col0 + j * 16;
    const f32x4 b2v = { b2[0 * D_ + cc], b2[1 * D_ + cc], b2[2 * D_ + cc], b2[3 * D_ + cc] };
#pragma unroll
    for (int i = 0; i < 4; ++i) {
      const int rr = row0 + i * 16;
#pragma unroll
      for (int r = 0; r < 4; ++r) {
        const f32x4 pr = *(const f32x4*)&probs[(size_t)(rr + r) * 4];
        const float bsum = pr[0]*b2v[0] + pr[1]*b2v[1] + pr[2]*b2v[2] + pr[3]*b2v[3];
        out[(size_t)(rr + r) * N + cc] =
            kv[(size_t)(rr + r) * N + cc] + sgf * (acc[i][j][r] + bsum);
      }
    }
  }
}

// ---------------------------------------------------------------------------
// MFMA flash attention, two segments, no-max exp2 softmax.
// Block = 512 thr (8 waves) handles (b, h, 128 q-rows); wave w: rows w*16..+16.
// Scores bounded (|s*scale*log2e| < ~8) -> softmax shift m=0 is exact; l is
// accumulated lane-locally (no shfl per tile), reduced once per segment.
// XCD-grouped swizzle: 4 q-tiles of one (b,h) share d%8.
// ---------------------------------------------------------------------------
__global__ __launch_bounds__(512, 2)
void attn_mfma_kernel(const bf16_t* __restrict__ qp, const bf16_t* __restrict__ kb,
                      const bf16_t* __restrict__ vt, bf16_t* __restrict__ attno,
                      const float* __restrict__ log_temp, const int* __restrict__ n_act) {
  __shared__ alignas(16) bf16_t Ks[2][64 * 64];
  __shared__ alignas(16) bf16_t Vs[2][64 * 64];
  __shared__ alignas(16) bf16_t Ps[8][16 * 64];

  // de-swizzle: blocks of one (b,h) land on the same XCD (d % 8 equal)
  const int dd = blockIdx.x;
  const int xcd = dd & 7, within = dd >> 3;
  const int qt = within & 3, slot = within >> 2;
  const int bh = slot * 8 + xcd;
  const int b = bh >> 4, h = bh & 15;

  const int tid = threadIdx.x;
  const int lane = tid & 63;
  const int w = tid >> 6;
  const int lane15 = lane & 15, lgrp = lane >> 4, l7 = lane & 7;
  const int Na = n_act[0];
  float temp = __expf(log_temp[0]);
  temp = fminf(fmaxf(temp, 0.1f), 10.0f);
  const float lsc = LOG2E / (64.0f * temp);   // exp2-domain scale
  const int q0 = qt * 128;

  // Q fragments (A-operand): row = lane15, k(d) = lgrp*8 (+32)
  const bf16_t* qsrc = qp + (size_t)(b * TQ_ + q0 + w * 16 + lane15) * D_ + h * 64 + lgrp * 8;
  const bf16x8 qf0 = *(const bf16x8*)qsrc;
  const bf16x8 qf1 = *(const bf16x8*)(qsrc + 32);

  // staging source (pre-swizzled chunk); 512 thr cover a 64x64 tile in one op
  const int srow = tid >> 3;                     // 0..63
  const int schunk = (tid & 7) ^ (srow & 7);
  const bf16_t* ksrc = kb + (size_t)(b * TK_ + srow) * D_ + h * 64 + schunk * 8;
  const bf16_t* vsrc = vt + ((size_t)(b * 16 + h) * 64 + srow) * TK_ + schunk * 8;

  f32x4 o[4] = {};
  f32x4 outa[4] = {};
  f32x4 lacc = {};

  const float inv_sa = rsqrtf((float)(Na > 1 ? Na : 1));
  const int Ni = TK_ - Na;
  const float inv_si = rsqrtf((float)(Ni > 1 ? Ni : 1));

  gld_lds16(ksrc, &Ks[0][tid * 8]);
  gld_lds16(vsrc, &Vs[0][tid * 8]);

  for (int t = 0; t < TK_ / 64; ++t) {
    const int cur = t & 1;
    __syncthreads();   // staging of tile t done; compute of t-1 done
    if (t + 1 < TK_ / 64) {
      const int nb = cur ^ 1;
      gld_lds16(ksrc + (size_t)(t + 1) * 64 * D_, &Ks[nb][tid * 8]);
      gld_lds16(vsrc + (size_t)(t + 1) * 64,      &Vs[nb][tid * 8]);
    }

    // ---- S = Q @ K^T : 8 MFMAs; sacc[cf] C-layout (col kpos, row q) ----
    f32x4 sacc[4];
#pragma unroll
    for (int cf = 0; cf < 4; ++cf) {
      const int krow = (cf * 16 + lane15) * 64;
      const bf16x8 kf0 = *(const bf16x8*)&Ks[cur][krow + ((lgrp ^ l7) << 3)];
      const bf16x8 kf1 = *(const bf16x8*)&Ks[cur][krow + (((lgrp + 4) ^ l7) << 3)];
      f32x4 s = {};
      s = __builtin_amdgcn_mfma_f32_16x16x32_bf16(qf0, kf0, s, 0, 0, 0);
      s = __builtin_amdgcn_mfma_f32_16x16x32_bf16(qf1, kf1, s, 0, 0, 0);
      sacc[cf] = s;
    }

    // ---- p = exp2(s*lsc); accumulate l lane-locally; write P swizzled ----
#pragma unroll
    for (int cf = 0; cf < 4; ++cf) {
      const int kp = cf * 16 + lane15;
      const int kcb = kp >> 3, kin = kp & 7;
      f32x4 p;
#pragma unroll
      for (int r = 0; r < 4; ++r) p[r] = exp2f(sacc[cf][r] * lsc);
      lacc += p;
#pragma unroll
      for (int r = 0; r < 4; ++r) {
        const int ql = lgrp * 4 + r;
        Ps[w][ql * 64 + ((kcb ^ (ql & 7)) << 3) + kin] = (bf16_t)p[r];
      }
    }

    // ---- O += P @ V ----
    {
      const int prow = lane15 * 64;
      const bf16x8 pa0 = *(const bf16x8*)&Ps[w][prow + ((lgrp ^ l7) << 3)];
      const bf16x8 pa1 = *(const bf16x8*)&Ps[w][prow + (((lgrp + 4) ^ l7) << 3)];
#pragma unroll
      for (int df = 0; df < 4; ++df) {
        const int vrow = (df * 16 + lane15) * 64;
        const bf16x8 vf0 = *(const bf16x8*)&Vs[cur][vrow + ((lgrp ^ l7) << 3)];
        const bf16x8 vf1 = *(const bf16x8*)&Vs[cur][vrow + (((lgrp + 4) ^ l7) << 3)];
        o[df] = __builtin_amdgcn_mfma_f32_16x16x32_bf16(pa0, vf0, o[df], 0, 0, 0);
        o[df] = __builtin_amdgcn_mfma_f32_16x16x32_bf16(pa1, vf1, o[df], 0, 0, 0);
      }
    }

    // ---- segment finalize ----
    const bool endA = ((t + 1) * 64 == Na);
    const bool endI = (t == TK_ / 64 - 1);
    if (endA || endI) {
      const float ssc = endA ? inv_sa : -inv_si;
      f32x4 rl = lacc;
#pragma unroll
      for (int r = 0; r < 4; ++r) {
        rl[r] += __shfl_xor(rl[r], 1);
        rl[r] += __shfl_xor(rl[r], 2);
        rl[r] += __shfl_xor(rl[r], 4);
        rl[r] += __shfl_xor(rl[r], 8);
      }
      f32x4 iv;
#pragma unroll
      for (int r = 0; r < 4; ++r) iv[r] = ssc / rl[r];
#pragma unroll
      for (int df = 0; df < 4; ++df) { outa[df] += o[df] * iv; o[df] = (f32x4){}; }
      lacc = (f32x4){};
    }
  }

#pragma unroll
  for (int df = 0; df < 4; ++df)
#pragma unroll
    for (int r = 0; r < 4; ++r)
      attno[(size_t)(b * TQ_ + q0 + w * 16 + lgrp * 4 + r) * D_ + h * 64 + df * 16 + lane15] =
          (bf16_t)outa[df][r];
}

// ---------------------------------------------------------------------------
// delta = rmsnorm(proj, dn_w); q_new = q + sigmoid(gate_attn)*delta (fp32 out)
// ---------------------------------------------------------------------------
__global__ __launch_bounds__(256)
void delta_qnew_kernel(const bf16_t* __restrict__ proj, const float* __restrict__ dn_w,
                       const float* __restrict__ q, const float* __restrict__ gate_attn,
                       float* __restrict__ qnew) {
  __shared__ float red[4];
  const int row = blockIdx.x;
  const int tid = threadIdx.x;
  bf16x4 pv = *(const bf16x4*)(proj + (size_t)row * D_ + tid * 4);
  f32x4 v;
#pragma unroll
  for (int c = 0; c < 4; ++c) v[c] = (float)pv[c];
  float ss = v[0]*v[0] + v[1]*v[1] + v[2]*v[2] + v[3]*v[3];
  ss = block_rsum(ss, red);
  const float rs = rsqrtf(ss * (1.0f / D_) + EPSF);
  const float sga = 1.0f / (1.0f + __expf(-gate_attn[0]));
  const int d = tid * 4;
  f32x4 wv = *(const f32x4*)(dn_w + d);
  f32x4 qv = *(const f32x4*)(q + (size_t)row * D_ + d);
  f32x4 out;
#pragma unroll
  for (int c = 0; c < 4; ++c) out[c] = qv[c] + sga * (v[c] * rs * wv[c]);
  *(f32x4*)&qnew[(size_t)row * D_ + d] = out;
}

// ---------------------------------------------------------------------------
extern "C" void kernel_launch(void* const* d_in, const int* in_sizes, int n_in,
                              void* d_out, int out_size, void* d_ws, size_t ws_size,
                              hipStream_t stream) {
  const float* q           = (const float*)d_in[0];
  const float* kv          = (const float*)d_in[1];
  const float* qn_w        = (const float*)d_in[2];
  const float* kva_w       = (const float*)d_in[3];
  const float* kvi_w       = (const float*)d_in[4];
  const float* dn_w        = (const float*)d_in[5];
  const float* fn_w        = (const float*)d_in[6];
  const float* Wq          = (const float*)d_in[7];
  const float* bq          = (const float*)d_in[8];
  const float* Wk          = (const float*)d_in[9];
  const float* bk          = (const float*)d_in[10];
  const float* Wv          = (const float*)d_in[11];
  const float* bv          = (const float*)d_in[12];
  const float* Wo          = (const float*)d_in[13];
  const float* bo          = (const float*)d_in[14];
  const float* active_bias = (const float*)d_in[15];
  const float* inactive_b  = (const float*)d_in[16];
  const float* log_temp    = (const float*)d_in[17];
  const float* gate_attn   = (const float*)d_in[18];
  const float* gate_ffn    = (const float*)d_in[19];
  const float* Wr          = (const float*)d_in[20];
  const float* br          = (const float*)d_in[21];
  const float* W1          = (const float*)d_in[22];
  const float* b1          = (const float*)d_in[23];
  const float* W2          = (const float*)d_in[24];
  const float* b2          = (const float*)d_in[25];
  // d_in[26] kv_mask: unused (all-true in reference forward)
  const int*   n_act       = (const int*)d_in[27];

  char* ws = (char*)d_ws;
  size_t off = 0;
  auto alloc = [&](size_t bytes) -> char* {
    char* p = ws + off;
    off = (off + bytes + 255) & ~(size_t)255;
    return p;
  };

  bf16_t* wqT  = (bf16_t*)alloc((size_t)D_ * D_ * 2);
  bf16_t* wkT  = (bf16_t*)alloc((size_t)D_ * D_ * 2);
  bf16_t* wvT  = (bf16_t*)alloc((size_t)D_ * D_ * 2);
  bf16_t* woT  = (bf16_t*)alloc((size_t)D_ * D_ * 2);
  bf16_t* w1T  = (bf16_t*)alloc((size_t)256 * D_ * 2);
  bf16_t* w2T  = (bf16_t*)alloc((size_t)D_ * 128 * 2);
  bf16_t* kvb  = (bf16_t*)alloc((size_t)B_ * TK_ * D_ * 2);
  bf16_t* xn   = (bf16_t*)alloc((size_t)B_ * TK_ * D_ * 2);
  bf16_t* qn   = (bf16_t*)alloc((size_t)B_ * TQ_ * D_ * 2);
  bf16_t* qp   = (bf16_t*)alloc((size_t)B_ * TQ_ * D_ * 2);
  bf16_t* kbuf = (bf16_t*)alloc((size_t)B_ * TK_ * D_ * 2);
  bf16_t* vt   = (bf16_t*)alloc((size_t)B_ * D_ * TK_ * 2);
  float*  probs = (float*)alloc((size_t)B_ * TK_ * NE_ * 4);
  // reuse (after last consumer):
  bf16_t* attno = qn;    // qn consumed by qp GEMM before attention writes
  bf16_t* proj  = qp;    // qp consumed by attention before proj GEMM writes
  bf16_t* a2buf = kbuf;  // kbuf consumed by attention before h-act writes
  (void)ws_size; (void)in_sizes; (void)n_in; (void)out_size;

  float* q_new_out  = (float*)d_out;
  float* kv_new_out = (float*)d_out + (size_t)B_ * TQ_ * D_;

  dim3 tb(32, 8);
  transpose_conv_kernel<<<dim3(32, 32, 1), tb, 0, stream>>>(Wq, wqT, D_, D_, 0, D_, 0, 0);
  transpose_conv_kernel<<<dim3(32, 32, 1), tb, 0, stream>>>(Wk, wkT, D_, D_, 0, D_, 0, 0);
  transpose_conv_kernel<<<dim3(32, 32, 1), tb, 0, stream>>>(Wv, wvT, D_, D_, 0, D_, 0, 0);
  transpose_conv_kernel<<<dim3(32, 32, 1), tb, 0, stream>>>(Wo, woT, D_, D_, 0, D_, 0, 0);
  transpose_conv_kernel<<<dim3(2, 32, 4), tb, 0, stream>>>(W1, w1T, D_, 64, D_ * 64, D_, 64, 0);
  transpose_conv_kernel<<<dim3(32, 1, 4), tb, 0, stream>>>(W2, w2T, 32, D_, 32 * D_, 128, 0, 32);

  rms_kv_kernel<<<B_ * TK_, 256, 0, stream>>>(kv, kva_w, kvi_w, fn_w, active_bias,
                                              inactive_b, n_act, Wr, br, kvb, xn, probs);
  rms_q_kernel<<<B_ * TQ_, 256, 0, stream>>>(q, qn_w, qn);

  gemm_tn<1><<<dim3(B_ * TQ_ / 128, D_ / 128), 256, 0, stream>>>(qn, wqT, bq, qp, B_ * TQ_, D_, D_);
  gemm_tn<1><<<dim3(B_ * TK_ / 128, D_ / 128), 256, 0, stream>>>(kvb, wkT, bk, kbuf, B_ * TK_, D_, D_);
  gemm_vt<<<dim3(D_ / 128, TK_ / 128, B_), 256, 0, stream>>>(wvT, kvb, bv, vt);

  attn_mfma_kernel<<<B_ * H_ * (TQ_ / 128), 512, 0, stream>>>(qp, kbuf, vt, attno, log_temp, n_act);

  gemm_tn<1><<<dim3(B_ * TQ_ / 128, D_ / 128), 256, 0, stream>>>(attno, woT, bo, proj, B_ * TQ_, D_, D_);
  delta_qnew_kernel<<<B_ * TQ_, 256, 0, stream>>>(proj, dn_w, q, gate_attn, q_new_out);

  gemm_h_act<<<dim3(B_ * TK_ / 128, 2), 256, 0, stream>>>(xn, w1T, b1, probs, a2buf);
  gemm_moe_kvnew<<<dim3(B_ * TK_ / 128, D_ / 128), 256, 0, stream>>>(a2buf, w2T, kv, probs, b2,
                                                                     gate_ffn, kv_new_out);
}

// Round 4
// 357.312 us; speedup vs baseline: 2.7464x; 1.0306x over previous
//
#include <hip/hip_runtime.h>
#include <hip/hip_bf16.h>
#include <stdint.h>

// ---------------------------------------------------------------------------
// TransformerBlock fused forward for MI355X (gfx950).
// Shapes (fixed): B=8 TQ=512 TK=2048 D=1024 H=16 HD=64 NE=4 HID=32 NA=512.
//
// Round 4:
//  * attn: swapped QK^T (mfma(K,Q)) -> P row is lane-local along kpos ->
//    packed bf16x4 ds_write_b64 P stores (4 vs 16) + Q pre-scaled in bf16
//    (scale mul removed from the per-tile loop); l via per-lane scalar.
//  * GEMMs: 2-phase prefetch double-buffered LDS (stage t+1 before compute t,
//    one barrier per K-step) — loads in flight under MFMA (T3 minimal).
//  * bijective XCD swizzle on gemm grid.x.
// ---------------------------------------------------------------------------

#define B_   8
#define TQ_  512
#define TK_  2048
#define D_   1024
#define H_   16
#define HD_  64
#define NE_  4
#define HID_ 32
#define EPSF 1e-6f
#define LOG2E 1.44269504f

typedef __bf16 bf16_t;
typedef __bf16 bf16x8 __attribute__((ext_vector_type(8)));
typedef __bf16 bf16x4 __attribute__((ext_vector_type(4)));
typedef float  f32x4  __attribute__((ext_vector_type(4)));

typedef __attribute__((address_space(1))) void gvoid_t;
typedef __attribute__((address_space(3))) void lvoid_t;

__device__ __forceinline__ void gld_lds16(const void* g, void* l) {
  __builtin_amdgcn_global_load_lds((gvoid_t*)g, (lvoid_t*)l, 16, 0, 0);
}

// ---------------------------------------------------------------------------
// Weight convert + transpose: out[(c + bz*ob_row)*out_rstride + bz*ob_col + r]
//   = (bf16) in[bz*in_bstride + r*C + c]
// ---------------------------------------------------------------------------
__global__ void transpose_conv_kernel(const float* __restrict__ in, bf16_t* __restrict__ out,
                                      int R, int C, int in_bstride,
                                      int out_rstride, int ob_row, int ob_col) {
  __shared__ float tile[32][33];
  const int bz = blockIdx.z;
  const int rb = blockIdx.y * 32, cb = blockIdx.x * 32;
  const int txi = threadIdx.x, tyi = threadIdx.y;
  const float* inp = in + (size_t)bz * in_bstride;
#pragma unroll
  for (int i = 0; i < 32; i += 8) {
    const int r = rb + tyi + i, c = cb + txi;
    if (r < R && c < C) tile[tyi + i][txi] = inp[(size_t)r * C + c];
  }
  __syncthreads();
#pragma unroll
  for (int i = 0; i < 32; i += 8) {
    const int orow = cb + tyi + i;
    const int ocol = rb + txi;
    if (orow < C && ocol < R)
      out[(size_t)(orow + bz * ob_row) * out_rstride + bz * ob_col + ocol] =
          (bf16_t)tile[txi][tyi + i];
  }
}

__device__ __forceinline__ float block_rsum(float v, float* red) {
  v += __shfl_xor(v, 1);  v += __shfl_xor(v, 2);  v += __shfl_xor(v, 4);
  v += __shfl_xor(v, 8);  v += __shfl_xor(v, 16); v += __shfl_xor(v, 32);
  const int tid = threadIdx.x;
  if ((tid & 63) == 0) red[tid >> 6] = v;
  __syncthreads();
  return red[0] + red[1] + red[2] + red[3];
}

// ---------------------------------------------------------------------------
// RMSNorm of kv -> kvb (seg weights+bias), xn = rmsnorm(kv,fn_w), AND
// probs = softmax(x @ Wr + br)  (sim term is a softmax shift: dead).
// ---------------------------------------------------------------------------
__global__ __launch_bounds__(256)
void rms_kv_kernel(const float* __restrict__ kv, const float* __restrict__ kva_w,
                   const float* __restrict__ kvi_w, const float* __restrict__ fn_w,
                   const float* __restrict__ ab, const float* __restrict__ ib,
                   const int* __restrict__ n_act, const float* __restrict__ Wr,
                   const float* __restrict__ br,
                   bf16_t* __restrict__ kvb, bf16_t* __restrict__ xn,
                   float* __restrict__ probs) {
  __shared__ float red[4];
  __shared__ f32x4 pred[4];
  const int row = blockIdx.x;
  const int t = row & (TK_ - 1);
  const int tid = threadIdx.x;
  const float* src = kv + (size_t)row * D_;
  f32x4 v = ((const f32x4*)src)[tid];
  float ss = v[0]*v[0] + v[1]*v[1] + v[2]*v[2] + v[3]*v[3];
  ss = block_rsum(ss, red);
  const float rs = rsqrtf(ss * (1.0f / D_) + EPSF);
  const int Na = n_act[0];
  const float* wsel = (t < Na) ? kva_w : kvi_w;
  const float* bsel = (t < Na) ? ab : ib;
  const int d = tid * 4;
  f32x4 wv = *(const f32x4*)(wsel + d);
  f32x4 bv = *(const f32x4*)(bsel + d);
  f32x4 fv = *(const f32x4*)(fn_w + d);
  bf16x4 o0, o1;
  f32x4 p4 = {};
#pragma unroll
  for (int c = 0; c < 4; ++c) {
    const float xv = v[c] * rs;
    const float xf = xv * fv[c];
    o0[c] = (bf16_t)(xv * wv[c] + bv[c]);
    o1[c] = (bf16_t)xf;
    const f32x4 w4 = *(const f32x4*)&Wr[(d + c) * 4];
    p4 += w4 * xf;
  }
  *(bf16x4*)&kvb[(size_t)row * D_ + d] = o0;
  *(bf16x4*)&xn [(size_t)row * D_ + d] = o1;
#pragma unroll
  for (int m = 1; m <= 32; m <<= 1) {
    p4[0] += __shfl_xor(p4[0], m); p4[1] += __shfl_xor(p4[1], m);
    p4[2] += __shfl_xor(p4[2], m); p4[3] += __shfl_xor(p4[3], m);
  }
  if ((tid & 63) == 0) pred[tid >> 6] = p4;
  __syncthreads();
  if (tid == 0) {
    f32x4 s = pred[0] + pred[1] + pred[2] + pred[3];
    s[0] += br[0]; s[1] += br[1]; s[2] += br[2]; s[3] += br[3];
    const float mx = fmaxf(fmaxf(s[0], s[1]), fmaxf(s[2], s[3]));
    const float e0 = __expf(s[0] - mx), e1 = __expf(s[1] - mx);
    const float e2 = __expf(s[2] - mx), e3 = __expf(s[3] - mx);
    const float inv = 1.0f / (e0 + e1 + e2 + e3);
    f32x4 pr = { e0 * inv, e1 * inv, e2 * inv, e3 * inv };
    *(f32x4*)&probs[row * 4] = pr;
  }
}

__global__ __launch_bounds__(256)
void rms_q_kernel(const float* __restrict__ q, const float* __restrict__ qn_w,
                  bf16_t* __restrict__ qn) {
  __shared__ float red[4];
  const int row = blockIdx.x;
  const int tid = threadIdx.x;
  const float* src = q + (size_t)row * D_;
  f32x4 v = ((const f32x4*)src)[tid];
  float ss = v[0]*v[0] + v[1]*v[1] + v[2]*v[2] + v[3]*v[3];
  ss = block_rsum(ss, red);
  const float rs = rsqrtf(ss * (1.0f / D_) + EPSF);
  const int d = tid * 4;
  f32x4 wv = *(const f32x4*)(qn_w + d);
  bf16x4 o0;
#pragma unroll
  for (int c = 0; c < 4; ++c) o0[c] = (bf16_t)(v[c] * rs * wv[c]);
  *(bf16x4*)&qn[(size_t)row * D_ + d] = o0;
}

// ---------------------------------------------------------------------------
// Shared GEMM mainloop: 128x128 tile, BK=32, double-buffered LDS with
// 2-phase prefetch (stage t+1 before compute t; one barrier per K-step).
// As/Bs: [2][4096] bf16. acc: 4x4 f32x4.
// ---------------------------------------------------------------------------
__device__ __forceinline__ void gemm_loop_db(const bf16_t* __restrict__ ga,
                                             const bf16_t* __restrict__ gb,
                                             bf16_t* As, bf16_t* Bs, int K,
                                             size_t rstep, int ar, int br2,
                                             int tid, f32x4 acc[4][4]) {
  gld_lds16(ga,         &As[tid * 8]);
  gld_lds16(ga + rstep, &As[2048 + tid * 8]);
  gld_lds16(gb,         &Bs[tid * 8]);
  gld_lds16(gb + rstep, &Bs[2048 + tid * 8]);
  int buf = 0;
  for (int k0 = 0; k0 < K; k0 += 32) {
    __syncthreads();   // drains staged loads of buf; prior reads of buf^1 done
    if (k0 + 32 < K) {
      const int nb = buf ^ 1;
      gld_lds16(ga + k0 + 32,         &As[nb * 4096 + tid * 8]);
      gld_lds16(ga + k0 + 32 + rstep, &As[nb * 4096 + 2048 + tid * 8]);
      gld_lds16(gb + k0 + 32,         &Bs[nb * 4096 + tid * 8]);
      gld_lds16(gb + k0 + 32 + rstep, &Bs[nb * 4096 + 2048 + tid * 8]);
    }
    bf16x8 af[4], bfr[4];
#pragma unroll
    for (int i = 0; i < 4; ++i) af[i]  = *(const bf16x8*)&As[buf * 4096 + ar  + i * 512];
#pragma unroll
    for (int j = 0; j < 4; ++j) bfr[j] = *(const bf16x8*)&Bs[buf * 4096 + br2 + j * 512];
#pragma unroll
    for (int i = 0; i < 4; ++i)
#pragma unroll
      for (int j = 0; j < 4; ++j)
        acc[i][j] = __builtin_amdgcn_mfma_f32_16x16x32_bf16(af[i], bfr[j], acc[i][j], 0, 0, 0);
    buf ^= 1;
  }
}

__device__ __forceinline__ int xcd_swz(int bx, int gx) {
  // bijective chunked remap when gx % 8 == 0 (all our grids)
  if ((gx & 7) == 0) { const int cpx = gx >> 3; return (bx & 7) * cpx + (bx >> 3); }
  return bx;
}

// ---------------------------------------------------------------------------
// bf16 MFMA GEMM: C(M,N) = A(M,K) @ Wt(N,K)^T (+bias), bf16 out.
// ---------------------------------------------------------------------------
template<int HAS_BIAS>
__global__ __launch_bounds__(256)
void gemm_tn(const bf16_t* __restrict__ A, const bf16_t* __restrict__ Wt,
             const float* __restrict__ bias, bf16_t* __restrict__ C,
             int M, int N, int K) {
  __shared__ alignas(16) bf16_t As[2 * 128 * 32];
  __shared__ alignas(16) bf16_t Bs[2 * 128 * 32];
  const int tid = threadIdx.x;
  const int lane = tid & 63;
  const int w = tid >> 6;
  const int wr = w >> 1, wc = w & 1;
  const int m0 = xcd_swz(blockIdx.x, gridDim.x) * 128;
  const int n0 = blockIdx.y * 128;

  f32x4 acc[4][4] = {};
  const int eidx = tid * 8;
  const int srow = eidx >> 5;
  const int scol = eidx & 31;
  const bf16_t* ga = A  + (size_t)(m0 + srow) * K + scol;
  const bf16_t* gb = Wt + (size_t)(n0 + srow) * K + scol;
  const int kb = (lane >> 4) * 8;
  const int ar  = (wr * 64 + (lane & 15)) * 32 + kb;
  const int br2 = (wc * 64 + (lane & 15)) * 32 + kb;

  gemm_loop_db(ga, gb, As, Bs, K, (size_t)64 * K, ar, br2, tid, acc);

  const int row0 = m0 + wr * 64 + ((lane >> 4) << 2);
  const int col0 = n0 + wc * 64 + (lane & 15);
#pragma unroll
  for (int j = 0; j < 4; ++j) {
    const int cc = col0 + j * 16;
    const float bv = HAS_BIAS ? bias[cc] : 0.0f;
#pragma unroll
    for (int i = 0; i < 4; ++i) {
      const int rr = row0 + i * 16;
#pragma unroll
      for (int r = 0; r < 4; ++r)
        C[(size_t)(rr + r) * N + cc] = (bf16_t)(acc[i][j][r] + bv);
    }
  }
}

// ---------------------------------------------------------------------------
// Batched transposed-output V GEMM: vt_b(n=h*64+d, t) = wvT@kvb_b^T + bv[n]
// ---------------------------------------------------------------------------
__global__ __launch_bounds__(256)
void gemm_vt(const bf16_t* __restrict__ A, const bf16_t* __restrict__ Wt0,
             const float* __restrict__ bias, bf16_t* __restrict__ C0) {
  __shared__ alignas(16) bf16_t As[2 * 128 * 32];
  __shared__ alignas(16) bf16_t Bs[2 * 128 * 32];
  const int K = D_, N = TK_;
  const bf16_t* Wt = Wt0 + (size_t)blockIdx.z * TK_ * D_;
  bf16_t* C = C0 + (size_t)blockIdx.z * D_ * TK_;
  const int tid = threadIdx.x;
  const int lane = tid & 63;
  const int w = tid >> 6;
  const int wr = w >> 1, wc = w & 1;
  const int m0 = blockIdx.x * 128;
  const int n0 = blockIdx.y * 128;

  f32x4 acc[4][4] = {};
  const int eidx = tid * 8;
  const int srow = eidx >> 5;
  const int scol = eidx & 31;
  const bf16_t* ga = A  + (size_t)(m0 + srow) * K + scol;
  const bf16_t* gb = Wt + (size_t)(n0 + srow) * K + scol;
  const int kb = (lane >> 4) * 8;
  const int ar  = (wr * 64 + (lane & 15)) * 32 + kb;
  const int br2 = (wc * 64 + (lane & 15)) * 32 + kb;

  gemm_loop_db(ga, gb, As, Bs, K, (size_t)64 * K, ar, br2, tid, acc);

  const int row0 = m0 + wr * 64 + ((lane >> 4) << 2);
  const int col0 = n0 + wc * 64 + (lane & 15);
#pragma unroll
  for (int i = 0; i < 4; ++i) {
    const int rr = row0 + i * 16;
#pragma unroll
    for (int r = 0; r < 4; ++r) {
      const float bv = bias[rr + r];
#pragma unroll
      for (int j = 0; j < 4; ++j)
        C[(size_t)(rr + r) * N + col0 + j * 16] = (bf16_t)(acc[i][j][r] + bv);
    }
  }
}

// ---------------------------------------------------------------------------
// h-GEMM with fused bias + SiLU-gate + probs weighting -> a2 (M x 128).
// ---------------------------------------------------------------------------
__global__ __launch_bounds__(256)
void gemm_h_act(const bf16_t* __restrict__ A, const bf16_t* __restrict__ Wt,
                const float* __restrict__ bias, const float* __restrict__ probs,
                bf16_t* __restrict__ a2) {
  __shared__ alignas(16) bf16_t As[2 * 128 * 32];
  __shared__ alignas(16) bf16_t Bs[2 * 128 * 32];
  const int K = D_;
  const int tid = threadIdx.x;
  const int lane = tid & 63;
  const int w = tid >> 6;
  const int wr = w >> 1, wc = w & 1;
  const int m0 = xcd_swz(blockIdx.x, gridDim.x) * 128;
  const int n0 = blockIdx.y * 128;

  f32x4 acc[4][4] = {};
  const int eidx = tid * 8;
  const int srow = eidx >> 5;
  const int scol = eidx & 31;
  const bf16_t* ga = A  + (size_t)(m0 + srow) * K + scol;
  const bf16_t* gb = Wt + (size_t)(n0 + srow) * K + scol;
  const int kb = (lane >> 4) * 8;
  const int ar  = (wr * 64 + (lane & 15)) * 32 + kb;
  const int br2 = (wc * 64 + (lane & 15)) * 32 + kb;

  gemm_loop_db(ga, gb, As, Bs, K, (size_t)64 * K, ar, br2, tid, acc);

  const int row0 = m0 + wr * 64 + ((lane >> 4) << 2);
  const int hbase = n0 + wc * 64 + (lane & 15);
  const int e = hbase >> 6;
#pragma unroll
  for (int j = 0; j < 2; ++j) {
    const int ch = hbase + j * 16;
    const float bx = bias[ch], bg = bias[ch + 32];
    const int ac = (ch & 63) + e * 32;
#pragma unroll
    for (int i = 0; i < 4; ++i) {
      const int rr = row0 + i * 16;
#pragma unroll
      for (int r = 0; r < 4; ++r) {
        const float xp = acc[i][j][r] + bx;
        const float g  = acc[i][j + 2][r] + bg;
        const float sg = 1.0f / (1.0f + __expf(-g));
        const float pr = probs[(size_t)(rr + r) * 4 + e];
        a2[(size_t)(rr + r) * 128 + ac] = (bf16_t)(pr * xp * g * sg);
      }
    }
  }
}

// ---------------------------------------------------------------------------
// moe-GEMM (K=128) with fused kv_new epilogue (fp32 out).
// ---------------------------------------------------------------------------
__global__ __launch_bounds__(256)
void gemm_moe_kvnew(const bf16_t* __restrict__ A, const bf16_t* __restrict__ Wt,
                    const float* __restrict__ kv, const float* __restrict__ probs,
                    const float* __restrict__ b2, const float* __restrict__ gate_ffn,
                    float* __restrict__ out) {
  __shared__ alignas(16) bf16_t As[2 * 128 * 32];
  __shared__ alignas(16) bf16_t Bs[2 * 128 * 32];
  const int K = 128, N = D_;
  const int tid = threadIdx.x;
  const int lane = tid & 63;
  const int w = tid >> 6;
  const int wr = w >> 1, wc = w & 1;
  const int m0 = xcd_swz(blockIdx.x, gridDim.x) * 128;
  const int n0 = blockIdx.y * 128;

  f32x4 acc[4][4] = {};
  const int eidx = tid * 8;
  const int srow = eidx >> 5;
  const int scol = eidx & 31;
  const bf16_t* ga = A  + (size_t)(m0 + srow) * K + scol;
  const bf16_t* gb = Wt + (size_t)(n0 + srow) * K + scol;
  const int kb = (lane >> 4) * 8;
  const int ar  = (wr * 64 + (lane & 15)) * 32 + kb;
  const int br2 = (wc * 64 + (lane & 15)) * 32 + kb;

  gemm_loop_db(ga, gb, As, Bs, K, (size_t)64 * K, ar, br2, tid, acc);

  const float sgf = 1.0f / (1.0f + __expf(-gate_ffn[0]));
  const int row0 = m0 + wr * 64 + ((lane >> 4) << 2);
  const int col0 = n0 + wc * 64 + (lane & 15);
#pragma unroll
  for (int j = 0; j < 4; ++j) {
    const int cc = col0 + j * 16;
    const f32x4 b2v = { b2[0 * D_ + cc], b2[1 * D_ + cc], b2[2 * D_ + cc], b2[3 * D_ + cc] };
#pragma unroll
    for (int i = 0; i < 4; ++i) {
      const int rr = row0 + i * 16;
#pragma unroll
      for (int r = 0; r < 4; ++r) {
        const f32x4 pr = *(const f32x4*)&probs[(size_t)(rr + r) * 4];
        const float bsum = pr[0]*b2v[0] + pr[1]*b2v[1] + pr[2]*b2v[2] + pr[3]*b2v[3];
        out[(size_t)(rr + r) * N + cc] =
            kv[(size_t)(rr + r) * N + cc] + sgf * (acc[i][j][r] + bsum);
      }
    }
  }
}

// ---------------------------------------------------------------------------
// MFMA flash attention, two segments, no-max exp2 softmax, swapped QK^T.
// Block = 512 thr (8 waves) = (b, h, 128 q-rows); wave w: rows w*16..+16.
// S^T = mfma(K, Q): lane holds q=lane15, kpos=cf*16+lgrp*4+r ->
// P stores are packed bf16x4 (ds_write_b64); scale pre-folded into Q (bf16).
// ---------------------------------------------------------------------------
__global__ __launch_bounds__(512, 2)
void attn_mfma_kernel(const bf16_t* __restrict__ qp, const bf16_t* __restrict__ kb,
                      const bf16_t* __restrict__ vt, bf16_t* __restrict__ attno,
                      const float* __restrict__ log_temp, const int* __restrict__ n_act) {
  __shared__ alignas(16) bf16_t Ks[2][64 * 64];
  __shared__ alignas(16) bf16_t Vs[2][64 * 64];
  __shared__ alignas(16) bf16_t Ps[8][16 * 64];

  const int dd = blockIdx.x;
  const int xcd = dd & 7, within = dd >> 3;
  const int qt = within & 3, slot0 = within >> 2;
  const int bh = slot0 * 8 + xcd;
  const int b = bh >> 4, h = bh & 15;

  const int tid = threadIdx.x;
  const int lane = tid & 63;
  const int w = tid >> 6;
  const int lane15 = lane & 15, lgrp = lane >> 4, l7 = lane & 7;
  const int Na = n_act[0];
  float temp = __expf(log_temp[0]);
  temp = fminf(fmaxf(temp, 0.1f), 10.0f);
  const float lsc = LOG2E / (64.0f * temp);   // folded into Q
  const int q0 = qt * 128;

  // Q B-frags, pre-scaled (q-col = lane15, d chunk = lgrp*8 (+32))
  const bf16_t* qsrc = qp + (size_t)(b * TQ_ + q0 + w * 16 + lane15) * D_ + h * 64 + lgrp * 8;
  bf16x8 qf0 = *(const bf16x8*)qsrc;
  bf16x8 qf1 = *(const bf16x8*)(qsrc + 32);
#pragma unroll
  for (int j = 0; j < 8; ++j) {
    qf0[j] = (bf16_t)((float)qf0[j] * lsc);
    qf1[j] = (bf16_t)((float)qf1[j] * lsc);
  }

  // staging source (pre-swizzled chunk); 512 thr cover a 64x64 tile per issue
  const int srow = tid >> 3;
  const int schunk = (tid & 7) ^ (srow & 7);
  const bf16_t* ksrc = kb + (size_t)(b * TK_ + srow) * D_ + h * 64 + schunk * 8;
  const bf16_t* vsrc = vt + ((size_t)(b * 16 + h) * 64 + srow) * TK_ + schunk * 8;

  f32x4 o[4] = {};
  f32x4 outa[4] = {};
  float lacc = 0.f;

  const float inv_sa = rsqrtf((float)(Na > 1 ? Na : 1));
  const int Ni = TK_ - Na;
  const float inv_si = rsqrtf((float)(Ni > 1 ? Ni : 1));

  gld_lds16(ksrc, &Ks[0][tid * 8]);
  gld_lds16(vsrc, &Vs[0][tid * 8]);

  for (int t = 0; t < TK_ / 64; ++t) {
    const int cur = t & 1;
    __syncthreads();
    if (t + 1 < TK_ / 64) {
      const int nb = cur ^ 1;
      gld_lds16(ksrc + (size_t)(t + 1) * 64 * D_, &Ks[nb][tid * 8]);
      gld_lds16(vsrc + (size_t)(t + 1) * 64,      &Vs[nb][tid * 8]);
    }

    // ---- S^T = K @ Q : sacc[cf] holds (q=lane15, kpos=cf*16+lgrp*4+r) ----
    f32x4 sacc[4];
#pragma unroll
    for (int cf = 0; cf < 4; ++cf) {
      const int krow = (cf * 16 + lane15) * 64;
      const bf16x8 kf0 = *(const bf16x8*)&Ks[cur][krow + ((lgrp ^ l7) << 3)];
      const bf16x8 kf1 = *(const bf16x8*)&Ks[cur][krow + (((lgrp + 4) ^ l7) << 3)];
      f32x4 s = {};
      s = __builtin_amdgcn_mfma_f32_16x16x32_bf16(kf0, qf0, s, 0, 0, 0);
      s = __builtin_amdgcn_mfma_f32_16x16x32_bf16(kf1, qf1, s, 0, 0, 0);
      sacc[cf] = s;
    }

    // ---- p = exp2(s); lane-local l; packed P store (4 x ds_write_b64) ----
#pragma unroll
    for (int cf = 0; cf < 4; ++cf) {
      f32x4 p;
#pragma unroll
      for (int r = 0; r < 4; ++r) p[r] = exp2f(sacc[cf][r]);
      lacc += (p[0] + p[1]) + (p[2] + p[3]);
      bf16x4 pv4;
#pragma unroll
      for (int r = 0; r < 4; ++r) pv4[r] = (bf16_t)p[r];
      const int c = cf * 2 + (lgrp >> 1);            // 8-wide kpos chunk id
      *(bf16x4*)&Ps[w][lane15 * 64 + ((c ^ l7) << 3) + (lgrp & 1) * 4] = pv4;
    }

    // ---- O += P @ V ----
    {
      const int prow = lane15 * 64;
      const bf16x8 pa0 = *(const bf16x8*)&Ps[w][prow + ((lgrp ^ l7) << 3)];
      const bf16x8 pa1 = *(const bf16x8*)&Ps[w][prow + (((lgrp + 4) ^ l7) << 3)];
#pragma unroll
      for (int df = 0; df < 4; ++df) {
        const int vrow = (df * 16 + lane15) * 64;
        const bf16x8 vf0 = *(const bf16x8*)&Vs[cur][vrow + ((lgrp ^ l7) << 3)];
        const bf16x8 vf1 = *(const bf16x8*)&Vs[cur][vrow + (((lgrp + 4) ^ l7) << 3)];
        o[df] = __builtin_amdgcn_mfma_f32_16x16x32_bf16(pa0, vf0, o[df], 0, 0, 0);
        o[df] = __builtin_amdgcn_mfma_f32_16x16x32_bf16(pa1, vf1, o[df], 0, 0, 0);
      }
    }

    // ---- segment finalize ----
    const bool endA = ((t + 1) * 64 == Na);
    const bool endI = (t == TK_ / 64 - 1);
    if (endA || endI) {
      float l = lacc;
      l += __shfl_xor(l, 16);
      l += __shfl_xor(l, 32);      // lane now holds total for q-row = lane15
      const float ssc = endA ? inv_sa : -inv_si;
      f32x4 iv;
#pragma unroll
      for (int r = 0; r < 4; ++r) iv[r] = ssc / __shfl(l, lgrp * 4 + r);
#pragma unroll
      for (int df = 0; df < 4; ++df) { outa[df] += o[df] * iv; o[df] = (f32x4){}; }
      lacc = 0.f;
    }
  }

  // O write: row = lgrp*4 + r, col = df*16 + lane15
#pragma unroll
  for (int df = 0; df < 4; ++df)
#pragma unroll
    for (int r = 0; r < 4; ++r)
      attno[(size_t)(b * TQ_ + q0 + w * 16 + lgrp * 4 + r) * D_ + h * 64 + df * 16 + lane15] =
          (bf16_t)outa[df][r];
}

// ---------------------------------------------------------------------------
// delta = rmsnorm(proj, dn_w); q_new = q + sigmoid(gate_attn)*delta (fp32 out)
// ---------------------------------------------------------------------------
__global__ __launch_bounds__(256)
void delta_qnew_kernel(const bf16_t* __restrict__ proj, const float* __restrict__ dn_w,
                       const float* __restrict__ q, const float* __restrict__ gate_attn,
                       float* __restrict__ qnew) {
  __shared__ float red[4];
  const int row = blockIdx.x;
  const int tid = threadIdx.x;
  bf16x4 pv = *(const bf16x4*)(proj + (size_t)row * D_ + tid * 4);
  f32x4 v;
#pragma unroll
  for (int c = 0; c < 4; ++c) v[c] = (float)pv[c];
  float ss = v[0]*v[0] + v[1]*v[1] + v[2]*v[2] + v[3]*v[3];
  ss = block_rsum(ss, red);
  const float rs = rsqrtf(ss * (1.0f / D_) + EPSF);
  const float sga = 1.0f / (1.0f + __expf(-gate_attn[0]));
  const int d = tid * 4;
  f32x4 wv = *(const f32x4*)(dn_w + d);
  f32x4 qv = *(const f32x4*)(q + (size_t)row * D_ + d);
  f32x4 out;
#pragma unroll
  for (int c = 0; c < 4; ++c) out[c] = qv[c] + sga * (v[c] * rs * wv[c]);
  *(f32x4*)&qnew[(size_t)row * D_ + d] = out;
}

// ---------------------------------------------------------------------------
extern "C" void kernel_launch(void* const* d_in, const int* in_sizes, int n_in,
                              void* d_out, int out_size, void* d_ws, size_t ws_size,
                              hipStream_t stream) {
  const float* q           = (const float*)d_in[0];
  const float* kv          = (const float*)d_in[1];
  const float* qn_w        = (const float*)d_in[2];
  const float* kva_w       = (const float*)d_in[3];
  const float* kvi_w       = (const float*)d_in[4];
  const float* dn_w        = (const float*)d_in[5];
  const float* fn_w        = (const float*)d_in[6];
  const float* Wq          = (const float*)d_in[7];
  const float* bq          = (const float*)d_in[8];
  const float* Wk          = (const float*)d_in[9];
  const float* bk          = (const float*)d_in[10];
  const float* Wv          = (const float*)d_in[11];
  const float* bv          = (const float*)d_in[12];
  const float* Wo          = (const float*)d_in[13];
  const float* bo          = (const float*)d_in[14];
  const float* active_bias = (const float*)d_in[15];
  const float* inactive_b  = (const float*)d_in[16];
  const float* log_temp    = (const float*)d_in[17];
  const float* gate_attn   = (const float*)d_in[18];
  const float* gate_ffn    = (const float*)d_in[19];
  const float* Wr          = (const float*)d_in[20];
  const float* br          = (const float*)d_in[21];
  const float* W1          = (const float*)d_in[22];
  const float* b1          = (const float*)d_in[23];
  const float* W2          = (const float*)d_in[24];
  const float* b2          = (const float*)d_in[25];
  const int*   n_act       = (const int*)d_in[27];

  char* ws = (char*)d_ws;
  size_t off = 0;
  auto alloc = [&](size_t bytes) -> char* {
    char* p = ws + off;
    off = (off + bytes + 255) & ~(size_t)255;
    return p;
  };

  bf16_t* wqT  = (bf16_t*)alloc((size_t)D_ * D_ * 2);
  bf16_t* wkT  = (bf16_t*)alloc((size_t)D_ * D_ * 2);
  bf16_t* wvT  = (bf16_t*)alloc((size_t)D_ * D_ * 2);
  bf16_t* woT  = (bf16_t*)alloc((size_t)D_ * D_ * 2);
  bf16_t* w1T  = (bf16_t*)alloc((size_t)256 * D_ * 2);
  bf16_t* w2T  = (bf16_t*)alloc((size_t)D_ * 128 * 2);
  bf16_t* kvb  = (bf16_t*)alloc((size_t)B_ * TK_ * D_ * 2);
  bf16_t* xn   = (bf16_t*)alloc((size_t)B_ * TK_ * D_ * 2);
  bf16_t* qn   = (bf16_t*)alloc((size_t)B_ * TQ_ * D_ * 2);
  bf16_t* qp   = (bf16_t*)alloc((size_t)B_ * TQ_ * D_ * 2);
  bf16_t* kbuf = (bf16_t*)alloc((size_t)B_ * TK_ * D_ * 2);
  bf16_t* vt   = (bf16_t*)alloc((size_t)B_ * D_ * TK_ * 2);
  float*  probs = (float*)alloc((size_t)B_ * TK_ * NE_ * 4);
  bf16_t* attno = qn;    // qn consumed by qp GEMM before attention writes
  bf16_t* proj  = qp;    // qp consumed by attention before proj GEMM writes
  bf16_t* a2buf = kbuf;  // kbuf consumed by attention before h-act writes
  (void)ws_size; (void)in_sizes; (void)n_in; (void)out_size;

  float* q_new_out  = (float*)d_out;
  float* kv_new_out = (float*)d_out + (size_t)B_ * TQ_ * D_;

  dim3 tb(32, 8);
  transpose_conv_kernel<<<dim3(32, 32, 1), tb, 0, stream>>>(Wq, wqT, D_, D_, 0, D_, 0, 0);
  transpose_conv_kernel<<<dim3(32, 32, 1), tb, 0, stream>>>(Wk, wkT, D_, D_, 0, D_, 0, 0);
  transpose_conv_kernel<<<dim3(32, 32, 1), tb, 0, stream>>>(Wv, wvT, D_, D_, 0, D_, 0, 0);
  transpose_conv_kernel<<<dim3(32, 32, 1), tb, 0, stream>>>(Wo, woT, D_, D_, 0, D_, 0, 0);
  transpose_conv_kernel<<<dim3(2, 32, 4), tb, 0, stream>>>(W1, w1T, D_, 64, D_ * 64, D_, 64, 0);
  transpose_conv_kernel<<<dim3(32, 1, 4), tb, 0, stream>>>(W2, w2T, 32, D_, 32 * D_, 128, 0, 32);

  rms_kv_kernel<<<B_ * TK_, 256, 0, stream>>>(kv, kva_w, kvi_w, fn_w, active_bias,
                                              inactive_b, n_act, Wr, br, kvb, xn, probs);
  rms_q_kernel<<<B_ * TQ_, 256, 0, stream>>>(q, qn_w, qn);

  gemm_tn<1><<<dim3(B_ * TQ_ / 128, D_ / 128), 256, 0, stream>>>(qn, wqT, bq, qp, B_ * TQ_, D_, D_);
  gemm_tn<1><<<dim3(B_ * TK_ / 128, D_ / 128), 256, 0, stream>>>(kvb, wkT, bk, kbuf, B_ * TK_, D_, D_);
  gemm_vt<<<dim3(D_ / 128, TK_ / 128, B_), 256, 0, stream>>>(wvT, kvb, bv, vt);

  attn_mfma_kernel<<<B_ * H_ * (TQ_ / 128), 512, 0, stream>>>(qp, kbuf, vt, attno, log_temp, n_act);

  gemm_tn<1><<<dim3(B_ * TQ_ / 128, D_ / 128), 256, 0, stream>>>(attno, woT, bo, proj, B_ * TQ_, D_, D_);
  delta_qnew_kernel<<<B_ * TQ_, 256, 0, stream>>>(proj, dn_w, q, gate_attn, q_new_out);

  gemm_h_act<<<dim3(B_ * TK_ / 128, 2), 256, 0, stream>>>(xn, w1T, b1, probs, a2buf);
  gemm_moe_kvnew<<<dim3(B_ * TK_ / 128, D_ / 128), 256, 0, stream>>>(a2buf, w2T, kv, probs, b2,
                                                                     gate_ffn, kv_new_out);
}

// Round 5
// 339.393 us; speedup vs baseline: 2.8914x; 1.0528x over previous
//
#include <hip/hip_runtime.h>
#include <hip/hip_bf16.h>
#include <stdint.h>

// ---------------------------------------------------------------------------
// TransformerBlock fused forward for MI355X (gfx950).
// Shapes (fixed): B=8 TQ=512 TK=2048 D=1024 H=16 HD=64 NE=4 HID=32 NA=512.
//
// Round 5:
//  * attn: LDS-throughput-bound (measured: 26 LDS ops/wave-tile * 12cyc
//    accounts for the full 70us). Wave now covers 32 q-rows (2 Q-frag sets)
//    so shared K/V frag reads amortize 2x: 28 ops / 32 rows (0.54x per row).
//    4-wave blocks (256 thr), LDS 48KB, 2-3 blocks/CU. setprio(1) on MFMA.
//  * qp/proj/h GEMMs: 256 blocks = 1/CU starvation regime -> 64x128 tiles
//    (512 blocks, 2/CU) so co-resident blocks cover the barrier drain.
//  * 4 DxD weight transposes batched into one launch.
// ---------------------------------------------------------------------------

#define B_   8
#define TQ_  512
#define TK_  2048
#define D_   1024
#define H_   16
#define HD_  64
#define NE_  4
#define HID_ 32
#define EPSF 1e-6f
#define LOG2E 1.44269504f

typedef __bf16 bf16_t;
typedef __bf16 bf16x8 __attribute__((ext_vector_type(8)));
typedef __bf16 bf16x4 __attribute__((ext_vector_type(4)));
typedef float  f32x4  __attribute__((ext_vector_type(4)));

typedef __attribute__((address_space(1))) void gvoid_t;
typedef __attribute__((address_space(3))) void lvoid_t;

__device__ __forceinline__ void gld_lds16(const void* g, void* l) {
  __builtin_amdgcn_global_load_lds((gvoid_t*)g, (lvoid_t*)l, 16, 0, 0);
}

// ---------------------------------------------------------------------------
// Batched 1024x1024 fp32 -> bf16 transpose (Wq,Wk,Wv,Wo in one launch).
// ---------------------------------------------------------------------------
struct TP4 { const float* in[4]; bf16_t* out[4]; };

__global__ void transpose_conv4_kernel(TP4 p) {
  __shared__ float tile[32][33];
  const int bz = blockIdx.z;
  const float* in = p.in[bz];
  bf16_t* out = p.out[bz];
  const int rb = blockIdx.y * 32, cb = blockIdx.x * 32;
  const int txi = threadIdx.x, tyi = threadIdx.y;
#pragma unroll
  for (int i = 0; i < 32; i += 8)
    tile[tyi + i][txi] = in[(size_t)(rb + tyi + i) * D_ + cb + txi];
  __syncthreads();
#pragma unroll
  for (int i = 0; i < 32; i += 8)
    out[(size_t)(cb + tyi + i) * D_ + rb + txi] = (bf16_t)tile[txi][tyi + i];
}

// Generic small transpose (W1/W2).
__global__ void transpose_conv_kernel(const float* __restrict__ in, bf16_t* __restrict__ out,
                                      int R, int C, int in_bstride,
                                      int out_rstride, int ob_row, int ob_col) {
  __shared__ float tile[32][33];
  const int bz = blockIdx.z;
  const int rb = blockIdx.y * 32, cb = blockIdx.x * 32;
  const int txi = threadIdx.x, tyi = threadIdx.y;
  const float* inp = in + (size_t)bz * in_bstride;
#pragma unroll
  for (int i = 0; i < 32; i += 8) {
    const int r = rb + tyi + i, c = cb + txi;
    if (r < R && c < C) tile[tyi + i][txi] = inp[(size_t)r * C + c];
  }
  __syncthreads();
#pragma unroll
  for (int i = 0; i < 32; i += 8) {
    const int orow = cb + tyi + i;
    const int ocol = rb + txi;
    if (orow < C && ocol < R)
      out[(size_t)(orow + bz * ob_row) * out_rstride + bz * ob_col + ocol] =
          (bf16_t)tile[txi][tyi + i];
  }
}

__device__ __forceinline__ float block_rsum(float v, float* red) {
  v += __shfl_xor(v, 1);  v += __shfl_xor(v, 2);  v += __shfl_xor(v, 4);
  v += __shfl_xor(v, 8);  v += __shfl_xor(v, 16); v += __shfl_xor(v, 32);
  const int tid = threadIdx.x;
  if ((tid & 63) == 0) red[tid >> 6] = v;
  __syncthreads();
  return red[0] + red[1] + red[2] + red[3];
}

// ---------------------------------------------------------------------------
// RMSNorm of kv -> kvb (seg weights+bias), xn = rmsnorm(kv,fn_w), AND
// probs = softmax(x @ Wr + br)  (sim term is a softmax shift: dead).
// ---------------------------------------------------------------------------
__global__ __launch_bounds__(256)
void rms_kv_kernel(const float* __restrict__ kv, const float* __restrict__ kva_w,
                   const float* __restrict__ kvi_w, const float* __restrict__ fn_w,
                   const float* __restrict__ ab, const float* __restrict__ ib,
                   const int* __restrict__ n_act, const float* __restrict__ Wr,
                   const float* __restrict__ br,
                   bf16_t* __restrict__ kvb, bf16_t* __restrict__ xn,
                   float* __restrict__ probs) {
  __shared__ float red[4];
  __shared__ f32x4 pred[4];
  const int row = blockIdx.x;
  const int t = row & (TK_ - 1);
  const int tid = threadIdx.x;
  const float* src = kv + (size_t)row * D_;
  f32x4 v = ((const f32x4*)src)[tid];
  float ss = v[0]*v[0] + v[1]*v[1] + v[2]*v[2] + v[3]*v[3];
  ss = block_rsum(ss, red);
  const float rs = rsqrtf(ss * (1.0f / D_) + EPSF);
  const int Na = n_act[0];
  const float* wsel = (t < Na) ? kva_w : kvi_w;
  const float* bsel = (t < Na) ? ab : ib;
  const int d = tid * 4;
  f32x4 wv = *(const f32x4*)(wsel + d);
  f32x4 bv = *(const f32x4*)(bsel + d);
  f32x4 fv = *(const f32x4*)(fn_w + d);
  bf16x4 o0, o1;
  f32x4 p4 = {};
#pragma unroll
  for (int c = 0; c < 4; ++c) {
    const float xv = v[c] * rs;
    const float xf = xv * fv[c];
    o0[c] = (bf16_t)(xv * wv[c] + bv[c]);
    o1[c] = (bf16_t)xf;
    const f32x4 w4 = *(const f32x4*)&Wr[(d + c) * 4];
    p4 += w4 * xf;
  }
  *(bf16x4*)&kvb[(size_t)row * D_ + d] = o0;
  *(bf16x4*)&xn [(size_t)row * D_ + d] = o1;
#pragma unroll
  for (int m = 1; m <= 32; m <<= 1) {
    p4[0] += __shfl_xor(p4[0], m); p4[1] += __shfl_xor(p4[1], m);
    p4[2] += __shfl_xor(p4[2], m); p4[3] += __shfl_xor(p4[3], m);
  }
  if ((tid & 63) == 0) pred[tid >> 6] = p4;
  __syncthreads();
  if (tid == 0) {
    f32x4 s = pred[0] + pred[1] + pred[2] + pred[3];
    s[0] += br[0]; s[1] += br[1]; s[2] += br[2]; s[3] += br[3];
    const float mx = fmaxf(fmaxf(s[0], s[1]), fmaxf(s[2], s[3]));
    const float e0 = __expf(s[0] - mx), e1 = __expf(s[1] - mx);
    const float e2 = __expf(s[2] - mx), e3 = __expf(s[3] - mx);
    const float inv = 1.0f / (e0 + e1 + e2 + e3);
    f32x4 pr = { e0 * inv, e1 * inv, e2 * inv, e3 * inv };
    *(f32x4*)&probs[row * 4] = pr;
  }
}

__global__ __launch_bounds__(256)
void rms_q_kernel(const float* __restrict__ q, const float* __restrict__ qn_w,
                  bf16_t* __restrict__ qn) {
  __shared__ float red[4];
  const int row = blockIdx.x;
  const int tid = threadIdx.x;
  const float* src = q + (size_t)row * D_;
  f32x4 v = ((const f32x4*)src)[tid];
  float ss = v[0]*v[0] + v[1]*v[1] + v[2]*v[2] + v[3]*v[3];
  ss = block_rsum(ss, red);
  const float rs = rsqrtf(ss * (1.0f / D_) + EPSF);
  const int d = tid * 4;
  f32x4 wv = *(const f32x4*)(qn_w + d);
  bf16x4 o0;
#pragma unroll
  for (int c = 0; c < 4; ++c) o0[c] = (bf16_t)(v[c] * rs * wv[c]);
  *(bf16x4*)&qn[(size_t)row * D_ + d] = o0;
}

__device__ __forceinline__ int xcd_swz(int bx, int gx) {
  if ((gx & 7) == 0) { const int cpx = gx >> 3; return (bx & 7) * cpx + (bx >> 3); }
  return bx;
}

// ---------------------------------------------------------------------------
// Shared 128x128 GEMM mainloop (BK=32, dbuf 2-phase prefetch).
// ---------------------------------------------------------------------------
__device__ __forceinline__ void gemm_loop_db(const bf16_t* __restrict__ ga,
                                             const bf16_t* __restrict__ gb,
                                             bf16_t* As, bf16_t* Bs, int K,
                                             size_t rstep, int ar, int br2,
                                             int tid, f32x4 acc[4][4]) {
  gld_lds16(ga,         &As[tid * 8]);
  gld_lds16(ga + rstep, &As[2048 + tid * 8]);
  gld_lds16(gb,         &Bs[tid * 8]);
  gld_lds16(gb + rstep, &Bs[2048 + tid * 8]);
  int buf = 0;
  for (int k0 = 0; k0 < K; k0 += 32) {
    __syncthreads();
    if (k0 + 32 < K) {
      const int nb = buf ^ 1;
      gld_lds16(ga + k0 + 32,         &As[nb * 4096 + tid * 8]);
      gld_lds16(ga + k0 + 32 + rstep, &As[nb * 4096 + 2048 + tid * 8]);
      gld_lds16(gb + k0 + 32,         &Bs[nb * 4096 + tid * 8]);
      gld_lds16(gb + k0 + 32 + rstep, &Bs[nb * 4096 + 2048 + tid * 8]);
    }
    bf16x8 af[4], bfr[4];
#pragma unroll
    for (int i = 0; i < 4; ++i) af[i]  = *(const bf16x8*)&As[buf * 4096 + ar  + i * 512];
#pragma unroll
    for (int j = 0; j < 4; ++j) bfr[j] = *(const bf16x8*)&Bs[buf * 4096 + br2 + j * 512];
#pragma unroll
    for (int i = 0; i < 4; ++i)
#pragma unroll
      for (int j = 0; j < 4; ++j)
        acc[i][j] = __builtin_amdgcn_mfma_f32_16x16x32_bf16(af[i], bfr[j], acc[i][j], 0, 0, 0);
    buf ^= 1;
  }
}

// ---------------------------------------------------------------------------
// Shared 64x128 GEMM mainloop (BK=32, dbuf) — for small-M GEMMs (2 blocks/CU).
// 4 waves as 2x2 over (32 rows x 64 cols); acc[2][4].
// ---------------------------------------------------------------------------
__device__ __forceinline__ void gemm64_loop_db(const bf16_t* __restrict__ ga,
                                               const bf16_t* __restrict__ gb,
                                               bf16_t* As, bf16_t* Bs, int K,
                                               size_t rstep, int ar, int br2,
                                               int tid, f32x4 acc[2][4]) {
  gld_lds16(ga,         &As[tid * 8]);
  gld_lds16(gb,         &Bs[tid * 8]);
  gld_lds16(gb + rstep, &Bs[2048 + tid * 8]);
  int buf = 0;
  for (int k0 = 0; k0 < K; k0 += 32) {
    __syncthreads();
    if (k0 + 32 < K) {
      const int nb = buf ^ 1;
      gld_lds16(ga + k0 + 32,         &As[nb * 2048 + tid * 8]);
      gld_lds16(gb + k0 + 32,         &Bs[nb * 4096 + tid * 8]);
      gld_lds16(gb + k0 + 32 + rstep, &Bs[nb * 4096 + 2048 + tid * 8]);
    }
    bf16x8 af[2], bfr[4];
#pragma unroll
    for (int i = 0; i < 2; ++i) af[i]  = *(const bf16x8*)&As[buf * 2048 + ar  + i * 512];
#pragma unroll
    for (int j = 0; j < 4; ++j) bfr[j] = *(const bf16x8*)&Bs[buf * 4096 + br2 + j * 512];
#pragma unroll
    for (int i = 0; i < 2; ++i)
#pragma unroll
      for (int j = 0; j < 4; ++j)
        acc[i][j] = __builtin_amdgcn_mfma_f32_16x16x32_bf16(af[i], bfr[j], acc[i][j], 0, 0, 0);
    buf ^= 1;
  }
}

// ---------------------------------------------------------------------------
// 128x128 GEMM: C = A @ Wt^T (+bias[N]) — used for k projection.
// ---------------------------------------------------------------------------
template<int HAS_BIAS>
__global__ __launch_bounds__(256)
void gemm_tn(const bf16_t* __restrict__ A, const bf16_t* __restrict__ Wt,
             const float* __restrict__ bias, bf16_t* __restrict__ C,
             int M, int N, int K) {
  __shared__ alignas(16) bf16_t As[2 * 128 * 32];
  __shared__ alignas(16) bf16_t Bs[2 * 128 * 32];
  const int tid = threadIdx.x;
  const int lane = tid & 63;
  const int w = tid >> 6;
  const int wr = w >> 1, wc = w & 1;
  const int m0 = xcd_swz(blockIdx.x, gridDim.x) * 128;
  const int n0 = blockIdx.y * 128;

  f32x4 acc[4][4] = {};
  const bf16_t* ga = A  + (size_t)(m0 + (tid >> 2)) * K + (tid & 3) * 8;
  const bf16_t* gb = Wt + (size_t)(n0 + (tid >> 2)) * K + (tid & 3) * 8;
  const int kb = (lane >> 4) * 8;
  const int ar  = ((wr * 64 + (lane & 15)) << 5) + kb;
  const int br2 = ((wc * 64 + (lane & 15)) << 5) + kb;

  gemm_loop_db(ga, gb, As, Bs, K, (size_t)64 * K, ar, br2, tid, acc);

  const int row0 = m0 + wr * 64 + ((lane >> 4) << 2);
  const int col0 = n0 + wc * 64 + (lane & 15);
#pragma unroll
  for (int j = 0; j < 4; ++j) {
    const int cc = col0 + j * 16;
    const float bv = HAS_BIAS ? bias[cc] : 0.0f;
#pragma unroll
    for (int i = 0; i < 4; ++i) {
      const int rr = row0 + i * 16;
#pragma unroll
      for (int r = 0; r < 4; ++r)
        C[(size_t)(rr + r) * N + cc] = (bf16_t)(acc[i][j][r] + bv);
    }
  }
}

// ---------------------------------------------------------------------------
// 64x128 GEMM: C = A @ Wt^T (+bias[N]) — qp / proj (small-M regime).
// ---------------------------------------------------------------------------
template<int HAS_BIAS>
__global__ __launch_bounds__(256)
void gemm64_tn(const bf16_t* __restrict__ A, const bf16_t* __restrict__ Wt,
               const float* __restrict__ bias, bf16_t* __restrict__ C,
               int M, int N, int K) {
  __shared__ alignas(16) bf16_t As[2 * 64 * 32];
  __shared__ alignas(16) bf16_t Bs[2 * 128 * 32];
  const int tid = threadIdx.x;
  const int lane = tid & 63;
  const int w = tid >> 6;
  const int wr = w >> 1, wc = w & 1;
  const int m0 = xcd_swz(blockIdx.x, gridDim.x) * 64;
  const int n0 = blockIdx.y * 128;

  f32x4 acc[2][4] = {};
  const bf16_t* ga = A  + (size_t)(m0 + (tid >> 2)) * K + (tid & 3) * 8;
  const bf16_t* gb = Wt + (size_t)(n0 + (tid >> 2)) * K + (tid & 3) * 8;
  const int kb = (lane >> 4) * 8;
  const int ar  = ((wr * 32 + (lane & 15)) << 5) + kb;
  const int br2 = ((wc * 64 + (lane & 15)) << 5) + kb;

  gemm64_loop_db(ga, gb, As, Bs, K, (size_t)64 * K, ar, br2, tid, acc);

  const int row0 = m0 + wr * 32 + ((lane >> 4) << 2);
  const int col0 = n0 + wc * 64 + (lane & 15);
#pragma unroll
  for (int j = 0; j < 4; ++j) {
    const int cc = col0 + j * 16;
    const float bv = HAS_BIAS ? bias[cc] : 0.0f;
#pragma unroll
    for (int i = 0; i < 2; ++i) {
      const int rr = row0 + i * 16;
#pragma unroll
      for (int r = 0; r < 4; ++r)
        C[(size_t)(rr + r) * N + cc] = (bf16_t)(acc[i][j][r] + bv);
    }
  }
}

// ---------------------------------------------------------------------------
// Batched transposed-output V GEMM: vt_b(n=h*64+d, t) = wvT@kvb_b^T + bv[n]
// ---------------------------------------------------------------------------
__global__ __launch_bounds__(256)
void gemm_vt(const bf16_t* __restrict__ A, const bf16_t* __restrict__ Wt0,
             const float* __restrict__ bias, bf16_t* __restrict__ C0) {
  __shared__ alignas(16) bf16_t As[2 * 128 * 32];
  __shared__ alignas(16) bf16_t Bs[2 * 128 * 32];
  const int K = D_, N = TK_;
  const bf16_t* Wt = Wt0 + (size_t)blockIdx.z * TK_ * D_;
  bf16_t* C = C0 + (size_t)blockIdx.z * D_ * TK_;
  const int tid = threadIdx.x;
  const int lane = tid & 63;
  const int w = tid >> 6;
  const int wr = w >> 1, wc = w & 1;
  const int m0 = blockIdx.x * 128;
  const int n0 = blockIdx.y * 128;

  f32x4 acc[4][4] = {};
  const bf16_t* ga = A  + (size_t)(m0 + (tid >> 2)) * K + (tid & 3) * 8;
  const bf16_t* gb = Wt + (size_t)(n0 + (tid >> 2)) * K + (tid & 3) * 8;
  const int kb = (lane >> 4) * 8;
  const int ar  = ((wr * 64 + (lane & 15)) << 5) + kb;
  const int br2 = ((wc * 64 + (lane & 15)) << 5) + kb;

  gemm_loop_db(ga, gb, As, Bs, K, (size_t)64 * K, ar, br2, tid, acc);

  const int row0 = m0 + wr * 64 + ((lane >> 4) << 2);
  const int col0 = n0 + wc * 64 + (lane & 15);
#pragma unroll
  for (int i = 0; i < 4; ++i) {
    const int rr = row0 + i * 16;
#pragma unroll
    for (int r = 0; r < 4; ++r) {
      const float bv = bias[rr + r];
#pragma unroll
      for (int j = 0; j < 4; ++j)
        C[(size_t)(rr + r) * N + col0 + j * 16] = (bf16_t)(acc[i][j][r] + bv);
    }
  }
}

// ---------------------------------------------------------------------------
// 64x128-tile h-GEMM with fused bias + SiLU-gate + probs weighting -> a2.
// ---------------------------------------------------------------------------
__global__ __launch_bounds__(256)
void gemm64_h_act(const bf16_t* __restrict__ A, const bf16_t* __restrict__ Wt,
                  const float* __restrict__ bias, const float* __restrict__ probs,
                  bf16_t* __restrict__ a2) {
  __shared__ alignas(16) bf16_t As[2 * 64 * 32];
  __shared__ alignas(16) bf16_t Bs[2 * 128 * 32];
  const int K = D_;
  const int tid = threadIdx.x;
  const int lane = tid & 63;
  const int w = tid >> 6;
  const int wr = w >> 1, wc = w & 1;
  const int m0 = xcd_swz(blockIdx.x, gridDim.x) * 64;
  const int n0 = blockIdx.y * 128;

  f32x4 acc[2][4] = {};
  const bf16_t* ga = A  + (size_t)(m0 + (tid >> 2)) * K + (tid & 3) * 8;
  const bf16_t* gb = Wt + (size_t)(n0 + (tid >> 2)) * K + (tid & 3) * 8;
  const int kb = (lane >> 4) * 8;
  const int ar  = ((wr * 32 + (lane & 15)) << 5) + kb;
  const int br2 = ((wc * 64 + (lane & 15)) << 5) + kb;

  gemm64_loop_db(ga, gb, As, Bs, K, (size_t)64 * K, ar, br2, tid, acc);

  const int row0 = m0 + wr * 32 + ((lane >> 4) << 2);
  const int hbase = n0 + wc * 64 + (lane & 15);
  const int e = hbase >> 6;
#pragma unroll
  for (int j = 0; j < 2; ++j) {
    const int ch = hbase + j * 16;
    const float bx = bias[ch], bg = bias[ch + 32];
    const int ac = (ch & 63) + e * 32;
#pragma unroll
    for (int i = 0; i < 2; ++i) {
      const int rr = row0 + i * 16;
#pragma unroll
      for (int r = 0; r < 4; ++r) {
        const float xp = acc[i][j][r] + bx;
        const float g  = acc[i][j + 2][r] + bg;
        const float sg = 1.0f / (1.0f + __expf(-g));
        const float pr = probs[(size_t)(rr + r) * 4 + e];
        a2[(size_t)(rr + r) * 128 + ac] = (bf16_t)(pr * xp * g * sg);
      }
    }
  }
}

// ---------------------------------------------------------------------------
// moe-GEMM (K=128) with fused kv_new epilogue (fp32 out).
// ---------------------------------------------------------------------------
__global__ __launch_bounds__(256)
void gemm_moe_kvnew(const bf16_t* __restrict__ A, const bf16_t* __restrict__ Wt,
                    const float* __restrict__ kv, const float* __restrict__ probs,
                    const float* __restrict__ b2, const float* __restrict__ gate_ffn,
                    float* __restrict__ out) {
  __shared__ alignas(16) bf16_t As[2 * 128 * 32];
  __shared__ alignas(16) bf16_t Bs[2 * 128 * 32];
  const int K = 128, N = D_;
  const int tid = threadIdx.x;
  const int lane = tid & 63;
  const int w = tid >> 6;
  const int wr = w >> 1, wc = w & 1;
  const int m0 = xcd_swz(blockIdx.x, gridDim.x) * 128;
  const int n0 = blockIdx.y * 128;

  f32x4 acc[4][4] = {};
  const bf16_t* ga = A  + (size_t)(m0 + (tid >> 2)) * K + (tid & 3) * 8;
  const bf16_t* gb = Wt + (size_t)(n0 + (tid >> 2)) * K + (tid & 3) * 8;
  const int kb = (lane >> 4) * 8;
  const int ar  = ((wr * 64 + (lane & 15)) << 5) + kb;
  const int br2 = ((wc * 64 + (lane & 15)) << 5) + kb;

  gemm_loop_db(ga, gb, As, Bs, K, (size_t)64 * K, ar, br2, tid, acc);

  const float sgf = 1.0f / (1.0f + __expf(-gate_ffn[0]));
  const int row0 = m0 + wr * 64 + ((lane >> 4) << 2);
  const int col0 = n0 + wc * 64 + (lane & 15);
#pragma unroll
  for (int j = 0; j < 4; ++j) {
    const int cc = col0 + j * 16;
    const f32x4 b2v = { b2[0 * D_ + cc], b2[1 * D_ + cc], b2[2 * D_ + cc], b2[3 * D_ + cc] };
#pragma unroll
    for (int i = 0; i < 4; ++i) {
      const int rr = row0 + i * 16;
#pragma unroll
      for (int r = 0; r < 4; ++r) {
        const f32x4 pr = *(const f32x4*)&probs[(size_t)(rr + r) * 4];
        const float bsum = pr[0]*b2v[0] + pr[1]*b2v[1] + pr[2]*b2v[2] + pr[3]*b2v[3];
        out[(size_t)(rr + r) * N + cc] =
            kv[(size_t)(rr + r) * N + cc] + sgf * (acc[i][j][r] + bsum);
      }
    }
  }
}

// ---------------------------------------------------------------------------
// MFMA flash attention, two segments, no-max exp2 softmax, swapped QK^T.
// Block = 256 thr (4 waves) = (b, h, 128 q-rows); wave w: 32 rows via TWO
// Q-fragment sets (A: rows w*32+lane15, B: +16) — K/V frag reads shared
// across both sets (LDS ops per q-row 0.54x vs 16-row waves).
// ---------------------------------------------------------------------------
__global__ __launch_bounds__(256, 3)
void attn_mfma_kernel(const bf16_t* __restrict__ qp, const bf16_t* __restrict__ kb,
                      const bf16_t* __restrict__ vt, bf16_t* __restrict__ attno,
                      const float* __restrict__ log_temp, const int* __restrict__ n_act) {
  __shared__ alignas(16) bf16_t Ks[2][64 * 64];
  __shared__ alignas(16) bf16_t Vs[2][64 * 64];
  __shared__ alignas(16) bf16_t Ps[4][32 * 64];

  const int dd = blockIdx.x;
  const int xcd = dd & 7, within = dd >> 3;
  const int qt = within & 3, slot0 = within >> 2;
  const int bh = slot0 * 8 + xcd;
  const int b = bh >> 4, h = bh & 15;

  const int tid = threadIdx.x;
  const int lane = tid & 63;
  const int w = tid >> 6;                       // 0..3
  const int lane15 = lane & 15, lgrp = lane >> 4, l7 = lane & 7;
  const int Na = n_act[0];
  float temp = __expf(log_temp[0]);
  temp = fminf(fmaxf(temp, 0.1f), 10.0f);
  const float lsc = LOG2E / (64.0f * temp);     // folded into Q
  const int rowbase = qt * 128 + w * 32;

  // Two Q B-frag sets, pre-scaled (q-col = lane15 / 16+lane15)
  const bf16_t* qsrcA = qp + (size_t)(b * TQ_ + rowbase + lane15) * D_ + h * 64 + lgrp * 8;
  const bf16_t* qsrcB = qsrcA + (size_t)16 * D_;
  bf16x8 qfA0 = *(const bf16x8*)qsrcA;
  bf16x8 qfA1 = *(const bf16x8*)(qsrcA + 32);
  bf16x8 qfB0 = *(const bf16x8*)qsrcB;
  bf16x8 qfB1 = *(const bf16x8*)(qsrcB + 32);
#pragma unroll
  for (int j = 0; j < 8; ++j) {
    qfA0[j] = (bf16_t)((float)qfA0[j] * lsc);
    qfA1[j] = (bf16_t)((float)qfA1[j] * lsc);
    qfB0[j] = (bf16_t)((float)qfB0[j] * lsc);
    qfB1[j] = (bf16_t)((float)qfB1[j] * lsc);
  }

  // staging source (pre-swizzled chunk); 256 thr cover 32 rows per issue,
  // two issues per 64x64 tile ((srow+32)&7 == srow&7 keeps the XOR valid).
  const int srow = tid >> 3;
  const int schunk = (tid & 7) ^ (srow & 7);
  const bf16_t* ksrc = kb + (size_t)(b * TK_ + srow) * D_ + h * 64 + schunk * 8;
  const bf16_t* vsrc = vt + ((size_t)(b * 16 + h) * 64 + srow) * TK_ + schunk * 8;

  f32x4 oA[4] = {}, oB[4] = {}, outA[4] = {}, outB[4] = {};
  float laccA = 0.f, laccB = 0.f;

  const float inv_sa = rsqrtf((float)(Na > 1 ? Na : 1));
  const int Ni = TK_ - Na;
  const float inv_si = rsqrtf((float)(Ni > 1 ? Ni : 1));

  gld_lds16(ksrc,            &Ks[0][tid * 8]);
  gld_lds16(ksrc + 32 * D_,  &Ks[0][2048 + tid * 8]);
  gld_lds16(vsrc,            &Vs[0][tid * 8]);
  gld_lds16(vsrc + 32 * TK_, &Vs[0][2048 + tid * 8]);

  for (int t = 0; t < TK_ / 64; ++t) {
    const int cur = t & 1;
    __syncthreads();
    if (t + 1 < TK_ / 64) {
      const int nb = cur ^ 1;
      const bf16_t* kN = ksrc + (size_t)(t + 1) * 64 * D_;
      const bf16_t* vN = vsrc + (size_t)(t + 1) * 64;
      gld_lds16(kN,            &Ks[nb][tid * 8]);
      gld_lds16(kN + 32 * D_,  &Ks[nb][2048 + tid * 8]);
      gld_lds16(vN,            &Vs[nb][tid * 8]);
      gld_lds16(vN + 32 * TK_, &Vs[nb][2048 + tid * 8]);
    }

    // ---- S^T = K @ Q for both sets (K frags shared) ----
    f32x4 sA[4], sB[4];
    __builtin_amdgcn_s_setprio(1);
#pragma unroll
    for (int cf = 0; cf < 4; ++cf) {
      const int krow = (cf * 16 + lane15) * 64;
      const bf16x8 kf0 = *(const bf16x8*)&Ks[cur][krow + ((lgrp ^ l7) << 3)];
      const bf16x8 kf1 = *(const bf16x8*)&Ks[cur][krow + (((lgrp + 4) ^ l7) << 3)];
      f32x4 s = {};
      s = __builtin_amdgcn_mfma_f32_16x16x32_bf16(kf0, qfA0, s, 0, 0, 0);
      s = __builtin_amdgcn_mfma_f32_16x16x32_bf16(kf1, qfA1, s, 0, 0, 0);
      sA[cf] = s;
      f32x4 s2 = {};
      s2 = __builtin_amdgcn_mfma_f32_16x16x32_bf16(kf0, qfB0, s2, 0, 0, 0);
      s2 = __builtin_amdgcn_mfma_f32_16x16x32_bf16(kf1, qfB1, s2, 0, 0, 0);
      sB[cf] = s2;
    }
    __builtin_amdgcn_s_setprio(0);

    // ---- p = exp2(s); lane-local l; packed bf16x4 P stores ----
#pragma unroll
    for (int cf = 0; cf < 4; ++cf) {
      const int c = cf * 2 + (lgrp >> 1);            // 8-wide kpos chunk id
      const int pcol = ((c ^ l7) << 3) + (lgrp & 1) * 4;
      f32x4 pA, pB;
#pragma unroll
      for (int r = 0; r < 4; ++r) pA[r] = exp2f(sA[cf][r]);
#pragma unroll
      for (int r = 0; r < 4; ++r) pB[r] = exp2f(sB[cf][r]);
      laccA += (pA[0] + pA[1]) + (pA[2] + pA[3]);
      laccB += (pB[0] + pB[1]) + (pB[2] + pB[3]);
      bf16x4 pvA, pvB;
#pragma unroll
      for (int r = 0; r < 4; ++r) { pvA[r] = (bf16_t)pA[r]; pvB[r] = (bf16_t)pB[r]; }
      *(bf16x4*)&Ps[w][lane15 * 64 + pcol]        = pvA;
      *(bf16x4*)&Ps[w][(16 + lane15) * 64 + pcol] = pvB;
    }

    // ---- O += P @ V for both sets (V frags shared) ----
    {
      const int prowA = lane15 * 64;
      const int prowB = (16 + lane15) * 64;
      const bf16x8 paA0 = *(const bf16x8*)&Ps[w][prowA + ((lgrp ^ l7) << 3)];
      const bf16x8 paA1 = *(const bf16x8*)&Ps[w][prowA + (((lgrp + 4) ^ l7) << 3)];
      const bf16x8 paB0 = *(const bf16x8*)&Ps[w][prowB + ((lgrp ^ l7) << 3)];
      const bf16x8 paB1 = *(const bf16x8*)&Ps[w][prowB + (((lgrp + 4) ^ l7) << 3)];
      __builtin_amdgcn_s_setprio(1);
#pragma unroll
      for (int df = 0; df < 4; ++df) {
        const int vrow = (df * 16 + lane15) * 64;
        const bf16x8 vf0 = *(const bf16x8*)&Vs[cur][vrow + ((lgrp ^ l7) << 3)];
        const bf16x8 vf1 = *(const bf16x8*)&Vs[cur][vrow + (((lgrp + 4) ^ l7) << 3)];
        oA[df] = __builtin_amdgcn_mfma_f32_16x16x32_bf16(paA0, vf0, oA[df], 0, 0, 0);
        oA[df] = __builtin_amdgcn_mfma_f32_16x16x32_bf16(paA1, vf1, oA[df], 0, 0, 0);
        oB[df] = __builtin_amdgcn_mfma_f32_16x16x32_bf16(paB0, vf0, oB[df], 0, 0, 0);
        oB[df] = __builtin_amdgcn_mfma_f32_16x16x32_bf16(paB1, vf1, oB[df], 0, 0, 0);
      }
      __builtin_amdgcn_s_setprio(0);
    }

    // ---- segment finalize ----
    const bool endA = ((t + 1) * 64 == Na);
    const bool endI = (t == TK_ / 64 - 1);
    if (endA || endI) {
      float lA = laccA, lB = laccB;
      lA += __shfl_xor(lA, 16); lA += __shfl_xor(lA, 32);
      lB += __shfl_xor(lB, 16); lB += __shfl_xor(lB, 32);
      const float ssc = endA ? inv_sa : -inv_si;
      f32x4 ivA, ivB;
#pragma unroll
      for (int r = 0; r < 4; ++r) {
        ivA[r] = ssc / __shfl(lA, lgrp * 4 + r);
        ivB[r] = ssc / __shfl(lB, lgrp * 4 + r);
      }
#pragma unroll
      for (int df = 0; df < 4; ++df) {
        outA[df] += oA[df] * ivA; oA[df] = (f32x4){};
        outB[df] += oB[df] * ivB; oB[df] = (f32x4){};
      }
      laccA = 0.f; laccB = 0.f;
    }
  }

  // O write: set A rows rowbase+lgrp*4+r, set B +16; col = df*16+lane15
#pragma unroll
  for (int df = 0; df < 4; ++df)
#pragma unroll
    for (int r = 0; r < 4; ++r) {
      const size_t ro = (size_t)(b * TQ_ + rowbase + lgrp * 4 + r) * D_ + h * 64 + df * 16 + lane15;
      attno[ro]             = (bf16_t)outA[df][r];
      attno[ro + 16 * D_]   = (bf16_t)outB[df][r];
    }
}

// ---------------------------------------------------------------------------
// delta = rmsnorm(proj, dn_w); q_new = q + sigmoid(gate_attn)*delta (fp32 out)
// ---------------------------------------------------------------------------
__global__ __launch_bounds__(256)
void delta_qnew_kernel(const bf16_t* __restrict__ proj, const float* __restrict__ dn_w,
                       const float* __restrict__ q, const float* __restrict__ gate_attn,
                       float* __restrict__ qnew) {
  __shared__ float red[4];
  const int row = blockIdx.x;
  const int tid = threadIdx.x;
  bf16x4 pv = *(const bf16x4*)(proj + (size_t)row * D_ + tid * 4);
  f32x4 v;
#pragma unroll
  for (int c = 0; c < 4; ++c) v[c] = (float)pv[c];
  float ss = v[0]*v[0] + v[1]*v[1] + v[2]*v[2] + v[3]*v[3];
  ss = block_rsum(ss, red);
  const float rs = rsqrtf(ss * (1.0f / D_) + EPSF);
  const float sga = 1.0f / (1.0f + __expf(-gate_attn[0]));
  const int d = tid * 4;
  f32x4 wv = *(const f32x4*)(dn_w + d);
  f32x4 qv = *(const f32x4*)(q + (size_t)row * D_ + d);
  f32x4 out;
#pragma unroll
  for (int c = 0; c < 4; ++c) out[c] = qv[c] + sga * (v[c] * rs * wv[c]);
  *(f32x4*)&qnew[(size_t)row * D_ + d] = out;
}

// ---------------------------------------------------------------------------
extern "C" void kernel_launch(void* const* d_in, const int* in_sizes, int n_in,
                              void* d_out, int out_size, void* d_ws, size_t ws_size,
                              hipStream_t stream) {
  const float* q           = (const float*)d_in[0];
  const float* kv          = (const float*)d_in[1];
  const float* qn_w        = (const float*)d_in[2];
  const float* kva_w       = (const float*)d_in[3];
  const float* kvi_w       = (const float*)d_in[4];
  const float* dn_w        = (const float*)d_in[5];
  const float* fn_w        = (const float*)d_in[6];
  const float* Wq          = (const float*)d_in[7];
  const float* bq          = (const float*)d_in[8];
  const float* Wk          = (const float*)d_in[9];
  const float* bk          = (const float*)d_in[10];
  const float* Wv          = (const float*)d_in[11];
  const float* bv          = (const float*)d_in[12];
  const float* Wo          = (const float*)d_in[13];
  const float* bo          = (const float*)d_in[14];
  const float* active_bias = (const float*)d_in[15];
  const float* inactive_b  = (const float*)d_in[16];
  const float* log_temp    = (const float*)d_in[17];
  const float* gate_attn   = (const float*)d_in[18];
  const float* gate_ffn    = (const float*)d_in[19];
  const float* Wr          = (const float*)d_in[20];
  const float* br          = (const float*)d_in[21];
  const float* W1          = (const float*)d_in[22];
  const float* b1          = (const float*)d_in[23];
  const float* W2          = (const float*)d_in[24];
  const float* b2          = (const float*)d_in[25];
  const int*   n_act       = (const int*)d_in[27];

  char* ws = (char*)d_ws;
  size_t off = 0;
  auto alloc = [&](size_t bytes) -> char* {
    char* p = ws + off;
    off = (off + bytes + 255) & ~(size_t)255;
    return p;
  };

  bf16_t* wqT  = (bf16_t*)alloc((size_t)D_ * D_ * 2);
  bf16_t* wkT  = (bf16_t*)alloc((size_t)D_ * D_ * 2);
  bf16_t* wvT  = (bf16_t*)alloc((size_t)D_ * D_ * 2);
  bf16_t* woT  = (bf16_t*)alloc((size_t)D_ * D_ * 2);
  bf16_t* w1T  = (bf16_t*)alloc((size_t)256 * D_ * 2);
  bf16_t* w2T  = (bf16_t*)alloc((size_t)D_ * 128 * 2);
  bf16_t* kvb  = (bf16_t*)alloc((size_t)B_ * TK_ * D_ * 2);
  bf16_t* xn   = (bf16_t*)alloc((size_t)B_ * TK_ * D_ * 2);
  bf16_t* qn   = (bf16_t*)alloc((size_t)B_ * TQ_ * D_ * 2);
  bf16_t* qp   = (bf16_t*)alloc((size_t)B_ * TQ_ * D_ * 2);
  bf16_t* kbuf = (bf16_t*)alloc((size_t)B_ * TK_ * D_ * 2);
  bf16_t* vt   = (bf16_t*)alloc((size_t)B_ * D_ * TK_ * 2);
  float*  probs = (float*)alloc((size_t)B_ * TK_ * NE_ * 4);
  bf16_t* attno = qn;    // qn consumed by qp GEMM before attention writes
  bf16_t* proj  = qp;    // qp consumed by attention before proj GEMM writes
  bf16_t* a2buf = kbuf;  // kbuf consumed by attention before h-act writes
  (void)ws_size; (void)in_sizes; (void)n_in; (void)out_size;

  float* q_new_out  = (float*)d_out;
  float* kv_new_out = (float*)d_out + (size_t)B_ * TQ_ * D_;

  dim3 tb(32, 8);
  TP4 tp;
  tp.in[0] = Wq; tp.in[1] = Wk; tp.in[2] = Wv; tp.in[3] = Wo;
  tp.out[0] = wqT; tp.out[1] = wkT; tp.out[2] = wvT; tp.out[3] = woT;
  transpose_conv4_kernel<<<dim3(32, 32, 4), tb, 0, stream>>>(tp);
  transpose_conv_kernel<<<dim3(2, 32, 4), tb, 0, stream>>>(W1, w1T, D_, 64, D_ * 64, D_, 64, 0);
  transpose_conv_kernel<<<dim3(32, 1, 4), tb, 0, stream>>>(W2, w2T, 32, D_, 32 * D_, 128, 0, 32);

  rms_kv_kernel<<<B_ * TK_, 256, 0, stream>>>(kv, kva_w, kvi_w, fn_w, active_bias,
                                              inactive_b, n_act, Wr, br, kvb, xn, probs);
  rms_q_kernel<<<B_ * TQ_, 256, 0, stream>>>(q, qn_w, qn);

  gemm64_tn<1><<<dim3(B_ * TQ_ / 64, D_ / 128), 256, 0, stream>>>(qn, wqT, bq, qp, B_ * TQ_, D_, D_);
  gemm_tn<1><<<dim3(B_ * TK_ / 128, D_ / 128), 256, 0, stream>>>(kvb, wkT, bk, kbuf, B_ * TK_, D_, D_);
  gemm_vt<<<dim3(D_ / 128, TK_ / 128, B_), 256, 0, stream>>>(wvT, kvb, bv, vt);

  attn_mfma_kernel<<<B_ * H_ * (TQ_ / 128), 256, 0, stream>>>(qp, kbuf, vt, attno, log_temp, n_act);

  gemm64_tn<1><<<dim3(B_ * TQ_ / 64, D_ / 128), 256, 0, stream>>>(attno, woT, bo, proj, B_ * TQ_, D_, D_);
  delta_qnew_kernel<<<B_ * TQ_, 256, 0, stream>>>(proj, dn_w, q, gate_attn, q_new_out);

  gemm64_h_act<<<dim3(B_ * TK_ / 64, 2), 256, 0, stream>>>(xn, w1T, b1, probs, a2buf);
  gemm_moe_kvnew<<<dim3(B_ * TK_ / 128, D_ / 128), 256, 0, stream>>>(a2buf, w2T, kv, probs, b2,
                                                                     gate_ffn, kv_new_out);
}